// Round 1
// baseline (1206.959 us; speedup 1.0000x reference)
//
#include <hip/hip_runtime.h>
#include <math.h>

#define NB 8
#define NG 4
#define NBG 32
#define NC 256
#define NH 32
#define NW 32
#define NHW 1024
#define NS 64
#define NHEADS 4
#define NDH 64
#define QSCALE 0.125f

// ---------------- q projection: per (b,g) 64x64 @ 64x1024 ----------------
__global__ __launch_bounds__(256) void k_qproj(const float* __restrict__ x,
                                               const float* __restrict__ wq,
                                               float* __restrict__ q) {
    __shared__ float Wst[64 * 64];   // [ci][co]
    __shared__ float xs[64 * 128];   // [ci][hw]
    int ht = blockIdx.x, g = blockIdx.y, b = blockIdx.z;
    int tid = threadIdx.x;
    for (int e = tid; e < 4096; e += 256) {
        int co = e >> 6, ci = e & 63;
        Wst[ci * 64 + co] = wq[(g * 64 + co) * 64 + ci];
    }
    const float* xb = x + (b * 256 + g * 64) * 1024 + ht * 128;
    for (int e = tid; e < 2048; e += 256) {
        int ci = e >> 5, hq = e & 31;
        *(float4*)&xs[ci * 128 + hq * 4] = *(const float4*)&xb[ci * 1024 + hq * 4];
    }
    __syncthreads();
    int cg = tid >> 4, hg = tid & 15;
    int co0 = cg * 4, hw0 = hg * 8;
    float acc[4][8];
    for (int a = 0; a < 4; a++) for (int c = 0; c < 8; c++) acc[a][c] = 0.f;
    for (int ci = 0; ci < 64; ci++) {
        float4 a4 = *(float4*)&Wst[ci * 64 + co0];
        float4 b0 = *(float4*)&xs[ci * 128 + hw0];
        float4 b1 = *(float4*)&xs[ci * 128 + hw0 + 4];
        float av[4] = {a4.x, a4.y, a4.z, a4.w};
        float bv[8] = {b0.x, b0.y, b0.z, b0.w, b1.x, b1.y, b1.z, b1.w};
        #pragma unroll
        for (int a = 0; a < 4; a++)
            #pragma unroll
            for (int c = 0; c < 8; c++) acc[a][c] += av[a] * bv[c];
    }
    float* qb = q + (b * 256 + g * 64) * 1024 + ht * 128;
    for (int a = 0; a < 4; a++) {
        float4 o0 = {acc[a][0], acc[a][1], acc[a][2], acc[a][3]};
        float4 o1 = {acc[a][4], acc[a][5], acc[a][6], acc[a][7]};
        *(float4*)&qb[(co0 + a) * 1024 + hw0] = o0;
        *(float4*)&qb[(co0 + a) * 1024 + hw0 + 4] = o1;
    }
}

// --------- offsets: dwconv6x6 s4 p1 + GELU + 1x1 + tanh*4 -> vgs ---------
__global__ __launch_bounds__(256) void k_offsets(const float* __restrict__ q,
                                                 const float* __restrict__ wdw,
                                                 const float* __restrict__ bdw,
                                                 const float* __restrict__ wpw,
                                                 float* __restrict__ vgs) {
    __shared__ float ws_dw[64 * 36];
    __shared__ float gelu_s[64 * 64];
    __shared__ float off_s[2 * 64];
    int n = blockIdx.x;
    int b = n >> 2, g = n & 3;
    int tid = threadIdx.x;
    for (int e = tid; e < 64 * 36; e += 256) ws_dw[e] = wdw[e];
    __syncthreads();
    const float* qn = q + (b * 256 + g * 64) * 1024;
    for (int e = tid; e < 4096; e += 256) {
        int c = e >> 6, pos = e & 63;
        int oy = pos >> 3, ox = pos & 7;
        float acc = bdw[c];
        for (int ky = 0; ky < 6; ky++) {
            int iy = oy * 4 - 1 + ky;
            if (iy < 0 || iy > 31) continue;
            for (int kx = 0; kx < 6; kx++) {
                int ix = ox * 4 - 1 + kx;
                if (ix < 0 || ix > 31) continue;
                acc += qn[c * 1024 + iy * 32 + ix] * ws_dw[c * 36 + ky * 6 + kx];
            }
        }
        gelu_s[c * 64 + pos] = acc * 0.5f * (1.f + erff(acc * 0.70710678118654752f));
    }
    __syncthreads();
    if (tid < 128) {
        int o = tid >> 6, pos = tid & 63;
        float a0 = 0.f, a1 = 0.f;
        for (int c = 0; c < 64; c += 2) {
            a0 += gelu_s[c * 64 + pos] * wpw[o * 64 + c];
            a1 += gelu_s[(c + 1) * 64 + pos] * wpw[o * 64 + c + 1];
        }
        off_s[o * 64 + pos] = tanhf(a0 + a1) * 4.0f;
    }
    __syncthreads();
    if (tid < 64) {
        int oy = tid >> 3, ox = tid & 7;
        float vx = 2.f * ((float)ox + off_s[tid]) / 7.f - 1.f;
        float vy = 2.f * ((float)oy + off_s[64 + tid]) / 7.f - 1.f;
        vgs[(n * 64 + tid) * 2]     = vx;
        vgs[(n * 64 + tid) * 2 + 1] = vy;
    }
}

// ------------- grid_sample (bilinear, zeros, align_corners=F) -------------
__global__ __launch_bounds__(256) void k_sample(const float* __restrict__ x,
                                                const float* __restrict__ vgs,
                                                float* __restrict__ kv) {
    int idx = blockIdx.x * 256 + threadIdx.x;   // 32*64*64
    int pos = idx & 63, c = (idx >> 6) & 63, n = idx >> 12;
    int b = n >> 2, g = n & 3;
    float gx = vgs[(n * 64 + pos) * 2];
    float gy = vgs[(n * 64 + pos) * 2 + 1];
    float ix = (gx + 1.f) * 16.f - 0.5f;
    float iy = (gy + 1.f) * 16.f - 0.5f;
    float x0 = floorf(ix), y0 = floorf(iy);
    float wa = (x0 + 1.f - ix) * (y0 + 1.f - iy);
    float wb = (ix - x0) * (y0 + 1.f - iy);
    float wc = (x0 + 1.f - ix) * (iy - y0);
    float wd = (ix - x0) * (iy - y0);
    const float* img = x + (b * 256 + g * 64 + c) * 1024;
    int xi = (int)x0, yi = (int)y0;
    float acc = 0.f;
    if (xi >= 0 && xi <= 31 && yi >= 0 && yi <= 31)         acc += img[yi * 32 + xi] * wa;
    if (xi + 1 >= 0 && xi + 1 <= 31 && yi >= 0 && yi <= 31) acc += img[yi * 32 + xi + 1] * wb;
    if (xi >= 0 && xi <= 31 && yi + 1 >= 0 && yi + 1 <= 31) acc += img[(yi + 1) * 32 + xi] * wc;
    if (xi + 1 >= 0 && xi + 1 <= 31 && yi + 1 >= 0 && yi + 1 <= 31) acc += img[(yi + 1) * 32 + xi + 1] * wd;
    kv[(n * 64 + c) * 64 + pos] = acc;
}

// ---------------- k,v projection: per (b,g) two 64x64 @ 64x64 -------------
__global__ __launch_bounds__(256) void k_kvproj(const float* __restrict__ kv,
                                                const float* __restrict__ wk,
                                                const float* __restrict__ wv,
                                                float* __restrict__ ko,
                                                float* __restrict__ vo) {
    __shared__ float kvs[4096];
    __shared__ float wkt[4096];
    __shared__ float wvt[4096];
    int n = blockIdx.x, g = n & 3;
    int tid = threadIdx.x;
    for (int e = tid; e < 4096; e += 256) {
        int co = e >> 6, ci = e & 63;
        wkt[ci * 64 + co] = wk[(g * 64 + co) * 64 + ci];
        wvt[ci * 64 + co] = wv[(g * 64 + co) * 64 + ci];
        kvs[e] = kv[n * 4096 + e];
    }
    __syncthreads();
    int cg = tid >> 4, jg = tid & 15;
    int co0 = cg * 4, j0 = jg * 4;
    float ak[4][4] = {}, av[4][4] = {};
    for (int ci = 0; ci < 64; ci++) {
        float4 a1 = *(float4*)&wkt[ci * 64 + co0];
        float4 a2 = *(float4*)&wvt[ci * 64 + co0];
        float4 b4 = *(float4*)&kvs[ci * 64 + j0];
        float w1v[4] = {a1.x, a1.y, a1.z, a1.w};
        float w2v[4] = {a2.x, a2.y, a2.z, a2.w};
        float bb[4] = {b4.x, b4.y, b4.z, b4.w};
        #pragma unroll
        for (int a = 0; a < 4; a++)
            #pragma unroll
            for (int j = 0; j < 4; j++) { ak[a][j] += w1v[a] * bb[j]; av[a][j] += w2v[a] * bb[j]; }
    }
    for (int a = 0; a < 4; a++) {
        float4 o1 = {ak[a][0], ak[a][1], ak[a][2], ak[a][3]};
        float4 o2 = {av[a][0], av[a][1], av[a][2], av[a][3]};
        *(float4*)&ko[n * 4096 + (co0 + a) * 64 + j0] = o1;
        *(float4*)&vo[n * 4096 + (co0 + a) * 64 + j0] = o2;
    }
}

// ------------------- CPB bias MLP (2->64->64->1) --------------------------
__global__ __launch_bounds__(256) void k_cpb(const float* __restrict__ vgs,
                                             const float* __restrict__ w1,
                                             const float* __restrict__ b1,
                                             const float* __restrict__ w2,
                                             const float* __restrict__ b2,
                                             const float* __restrict__ w3,
                                             const float* __restrict__ b3,
                                             float* __restrict__ bias) {
    __shared__ float w2s[4096];
    __shared__ float w1s[128];
    __shared__ float b1s[64], b2s[64], w3s[64];
    __shared__ float gkv[128];
    int it = blockIdx.x, n = blockIdx.y;
    int tid = threadIdx.x;
    for (int e = tid; e < 4096; e += 256) w2s[e] = w2[e];
    if (tid < 128) { w1s[tid] = w1[tid]; gkv[tid] = vgs[n * 128 + tid]; }
    if (tid < 64) { b1s[tid] = b1[tid]; b2s[tid] = b2[tid]; w3s[tid] = w3[tid]; }
    __syncthreads();
    float b3v = b3[0];
    int j = tid & 63;
    int ibase = tid >> 6;
    float kx = gkv[j * 2], ky = gkv[j * 2 + 1];
    for (int k = 0; k < 16; k++) {
        int il = ibase + k * 4;
        int iG = it * 64 + il;
        float qx = 2.f * (float)(iG & 31) / 31.f - 1.f;
        float qy = 2.f * (float)(iG >> 5) / 31.f - 1.f;
        float p0 = qx - kx, p1 = qy - ky;
        float u0 = copysignf(log1pf(fabsf(p0)), p0);
        float u1 = copysignf(log1pf(fabsf(p1)), p1);
        float h1[64];
        #pragma unroll
        for (int c = 0; c < 64; c++)
            h1[c] = fmaxf(w1s[2 * c] * u0 + w1s[2 * c + 1] * u1 + b1s[c], 0.f);
        float bacc = b3v;
        for (int c2 = 0; c2 < 64; c2++) {
            float d0 = 0.f, d1 = 0.f, d2 = 0.f, d3 = 0.f;
            #pragma unroll
            for (int cq = 0; cq < 16; cq++) {
                float4 wv4 = *(float4*)&w2s[c2 * 64 + cq * 4];
                d0 += wv4.x * h1[cq * 4];
                d1 += wv4.y * h1[cq * 4 + 1];
                d2 += wv4.z * h1[cq * 4 + 2];
                d3 += wv4.w * h1[cq * 4 + 3];
            }
            float d = b2s[c2] + ((d0 + d1) + (d2 + d3));
            bacc += w3s[c2] * fmaxf(d, 0.f);
        }
        bias[(n * 1024 + iG) * 64 + j] = bacc;
    }
}

// --------- fused attention: sim + bias + softmax + PV per (b,h,i64) -------
__global__ __launch_bounds__(256) void k_attn(const float* __restrict__ q,
                                              const float* __restrict__ kk,
                                              const float* __restrict__ vv,
                                              const float* __restrict__ bias,
                                              float* __restrict__ att_out) {
    __shared__ float sm[3 * 4352];
    float* qs = sm;                 // [i*68 + d]
    float* ks = sm + 4352;          // [j*68 + d]
    float* vs = sm + 8704;          // [j*68 + d]
    float* pst = sm;                // overlays qs after sim phase: [j*68 + i]
    int it = blockIdx.x, h = blockIdx.y, b = blockIdx.z;
    int i0 = it * 64;
    int n = b * 4 + h;
    int tid = threadIdx.x;
    for (int e = tid; e < 4096; e += 256) {
        int d = e >> 6, r = e & 63;
        qs[r * 68 + d] = q[(b * 256 + h * 64 + d) * 1024 + i0 + r] * QSCALE;
        ks[r * 68 + d] = kk[n * 4096 + d * 64 + r];
        vs[r * 68 + d] = vv[n * 4096 + d * 64 + r];
    }
    __syncthreads();
    int i = tid >> 2, jq = tid & 3;
    float s[16];
    const float* brow = bias + (n * 1024 + i0 + i) * 64 + jq * 16;
    for (int jj = 0; jj < 16; jj++) {
        int j = jq * 16 + jj;
        float d0 = 0.f, d1 = 0.f, d2 = 0.f, d3 = 0.f;
        #pragma unroll
        for (int dq = 0; dq < 16; dq++) {
            float4 qv = *(float4*)&qs[i * 68 + dq * 4];
            float4 kv4 = *(float4*)&ks[j * 68 + dq * 4];
            d0 += qv.x * kv4.x; d1 += qv.y * kv4.y;
            d2 += qv.z * kv4.z; d3 += qv.w * kv4.w;
        }
        s[jj] = ((d0 + d1) + (d2 + d3)) + brow[jj];
    }
    float m = s[0];
    for (int jj = 1; jj < 16; jj++) m = fmaxf(m, s[jj]);
    m = fmaxf(m, __shfl_xor(m, 1));
    m = fmaxf(m, __shfl_xor(m, 2));
    float sum = 0.f;
    for (int jj = 0; jj < 16; jj++) { s[jj] = expf(s[jj] - m); sum += s[jj]; }
    sum += __shfl_xor(sum, 1);
    sum += __shfl_xor(sum, 2);
    float inv = 1.f / sum;
    __syncthreads();   // everyone done reading qs
    for (int jj = 0; jj < 16; jj++) pst[(jq * 16 + jj) * 68 + i] = s[jj] * inv;
    __syncthreads();
    int ii = tid & 63, dq = tid >> 6;
    float acc[16] = {};
    for (int j = 0; j < 64; j++) {
        float pv = pst[j * 68 + ii];
        float4 v0 = *(float4*)&vs[j * 68 + dq * 16];
        float4 v1 = *(float4*)&vs[j * 68 + dq * 16 + 4];
        float4 v2 = *(float4*)&vs[j * 68 + dq * 16 + 8];
        float4 v3 = *(float4*)&vs[j * 68 + dq * 16 + 12];
        float vvv[16] = {v0.x, v0.y, v0.z, v0.w, v1.x, v1.y, v1.z, v1.w,
                         v2.x, v2.y, v2.z, v2.w, v3.x, v3.y, v3.z, v3.w};
        #pragma unroll
        for (int dd = 0; dd < 16; dd++) acc[dd] += pv * vvv[dd];
    }
    for (int dd = 0; dd < 16; dd++)
        att_out[(b * 256 + h * 64 + dq * 16 + dd) * 1024 + i0 + ii] = acc[dd];
}

// ---------------- output projection: per b 256x256 @ 256x1024 -------------
__global__ __launch_bounds__(256) void k_outproj(const float* __restrict__ att,
                                                 const float* __restrict__ wout,
                                                 const float* __restrict__ bout,
                                                 float* __restrict__ y) {
    __shared__ float Wt[64 * 128];   // [ci][co]
    __shared__ float as[64 * 128];   // [ci][hw]
    int ht = blockIdx.x, ct = blockIdx.y, b = blockIdx.z;
    int tid = threadIdx.x;
    int cg = tid >> 4, hg = tid & 15;
    int co0 = cg * 8, hw0 = hg * 8;
    float acc[8][8] = {};
    for (int kt = 0; kt < 4; kt++) {
        __syncthreads();
        for (int e = tid; e < 8192; e += 256) {
            int co = e >> 6, ci = e & 63;
            Wt[ci * 128 + co] = wout[(ct * 128 + co) * 256 + kt * 64 + ci];
        }
        for (int e = tid; e < 2048; e += 256) {
            int ci = e >> 5, hq = e & 31;
            *(float4*)&as[ci * 128 + hq * 4] =
                *(const float4*)&att[(b * 256 + kt * 64 + ci) * 1024 + ht * 128 + hq * 4];
        }
        __syncthreads();
        for (int ci = 0; ci < 64; ci++) {
            float4 a0 = *(float4*)&Wt[ci * 128 + co0];
            float4 a1 = *(float4*)&Wt[ci * 128 + co0 + 4];
            float4 b0 = *(float4*)&as[ci * 128 + hw0];
            float4 b1 = *(float4*)&as[ci * 128 + hw0 + 4];
            float av[8] = {a0.x, a0.y, a0.z, a0.w, a1.x, a1.y, a1.z, a1.w};
            float bv[8] = {b0.x, b0.y, b0.z, b0.w, b1.x, b1.y, b1.z, b1.w};
            #pragma unroll
            for (int a = 0; a < 8; a++)
                #pragma unroll
                for (int c = 0; c < 8; c++) acc[a][c] += av[a] * bv[c];
        }
    }
    for (int a = 0; a < 8; a++) {
        int co = ct * 128 + co0 + a;
        float bo = bout[co];
        float4 o0 = {acc[a][0] + bo, acc[a][1] + bo, acc[a][2] + bo, acc[a][3] + bo};
        float4 o1 = {acc[a][4] + bo, acc[a][5] + bo, acc[a][6] + bo, acc[a][7] + bo};
        *(float4*)&y[(b * 256 + co) * 1024 + ht * 128 + hw0] = o0;
        *(float4*)&y[(b * 256 + co) * 1024 + ht * 128 + hw0 + 4] = o1;
    }
}

extern "C" void kernel_launch(void* const* d_in, const int* in_sizes, int n_in,
                              void* d_out, int out_size, void* d_ws, size_t ws_size,
                              hipStream_t stream) {
    const float* x    = (const float*)d_in[0];
    const float* wq   = (const float*)d_in[1];
    const float* wk   = (const float*)d_in[2];
    const float* wv   = (const float*)d_in[3];
    const float* wdw  = (const float*)d_in[4];
    const float* bdw  = (const float*)d_in[5];
    const float* wpw  = (const float*)d_in[6];
    const float* cw1  = (const float*)d_in[7];
    const float* cb1  = (const float*)d_in[8];
    const float* cw2  = (const float*)d_in[9];
    const float* cb2  = (const float*)d_in[10];
    const float* cw3  = (const float*)d_in[11];
    const float* cb3  = (const float*)d_in[12];
    const float* wout = (const float*)d_in[13];
    const float* bout = (const float*)d_in[14];
    float* y  = (float*)d_out;
    float* ws = (float*)d_ws;

    float* q    = ws;                    // 2,097,152
    float* att  = ws + 2097152;          // 2,097,152
    float* bias = ws + 4194304;          // 2,097,152
    float* kv   = ws + 6291456;          // 131,072
    float* kbuf = ws + 6422528;          // 131,072
    float* vbuf = ws + 6553600;          // 131,072
    float* vgs  = ws + 6684672;          // 4,096

    k_qproj  <<<dim3(8, 4, 8),  256, 0, stream>>>(x, wq, q);
    k_offsets<<<32,             256, 0, stream>>>(q, wdw, bdw, wpw, vgs);
    k_sample <<<512,            256, 0, stream>>>(x, vgs, kv);
    k_kvproj <<<32,             256, 0, stream>>>(kv, wk, wv, kbuf, vbuf);
    k_cpb    <<<dim3(16, 32),   256, 0, stream>>>(vgs, cw1, cb1, cw2, cb2, cw3, cb3, bias);
    k_attn   <<<dim3(16, 4, 8), 256, 0, stream>>>(q, kbuf, vbuf, bias, att);
    k_outproj<<<dim3(8, 2, 8),  256, 0, stream>>>(att, wout, bout, y);
}

// Round 2
// 231.223 us; speedup vs baseline: 5.2199x; 5.2199x over previous
//
#include <hip/hip_runtime.h>
#include <hip/hip_bf16.h>
#include <math.h>

#define QSCALE 0.125f

typedef __attribute__((ext_vector_type(8))) short short8b;   // 8 bf16 (4 VGPRs)
typedef __attribute__((ext_vector_type(4))) float f32x4;

// ---------------- q projection: per (b,g) 64x64 @ 64x1024 ----------------
__global__ __launch_bounds__(256) void k_qproj(const float* __restrict__ x,
                                               const float* __restrict__ wq,
                                               float* __restrict__ q) {
    __shared__ float Wst[64 * 64];   // [ci][co]
    __shared__ float xs[64 * 128];   // [ci][hw]
    int ht = blockIdx.x, g = blockIdx.y, b = blockIdx.z;
    int tid = threadIdx.x;
    for (int e = tid; e < 4096; e += 256) {
        int co = e >> 6, ci = e & 63;
        Wst[ci * 64 + co] = wq[(g * 64 + co) * 64 + ci];
    }
    const float* xb = x + (b * 256 + g * 64) * 1024 + ht * 128;
    for (int e = tid; e < 2048; e += 256) {
        int ci = e >> 5, hq = e & 31;
        *(float4*)&xs[ci * 128 + hq * 4] = *(const float4*)&xb[ci * 1024 + hq * 4];
    }
    __syncthreads();
    int cg = tid >> 4, hg = tid & 15;
    int co0 = cg * 4, hw0 = hg * 8;
    float acc[4][8];
    for (int a = 0; a < 4; a++) for (int c = 0; c < 8; c++) acc[a][c] = 0.f;
    for (int ci = 0; ci < 64; ci++) {
        float4 a4 = *(float4*)&Wst[ci * 64 + co0];
        float4 b0 = *(float4*)&xs[ci * 128 + hw0];
        float4 b1 = *(float4*)&xs[ci * 128 + hw0 + 4];
        float av[4] = {a4.x, a4.y, a4.z, a4.w};
        float bv[8] = {b0.x, b0.y, b0.z, b0.w, b1.x, b1.y, b1.z, b1.w};
        #pragma unroll
        for (int a = 0; a < 4; a++)
            #pragma unroll
            for (int c = 0; c < 8; c++) acc[a][c] += av[a] * bv[c];
    }
    float* qb = q + (b * 256 + g * 64) * 1024 + ht * 128;
    for (int a = 0; a < 4; a++) {
        float4 o0 = {acc[a][0], acc[a][1], acc[a][2], acc[a][3]};
        float4 o1 = {acc[a][4], acc[a][5], acc[a][6], acc[a][7]};
        *(float4*)&qb[(co0 + a) * 1024 + hw0] = o0;
        *(float4*)&qb[(co0 + a) * 1024 + hw0 + 4] = o1;
    }
}

// --------- offsets: dwconv6x6 s4 p1 + GELU + 1x1 + tanh*4 -> vgs ---------
__global__ __launch_bounds__(256) void k_offsets(const float* __restrict__ q,
                                                 const float* __restrict__ wdw,
                                                 const float* __restrict__ bdw,
                                                 const float* __restrict__ wpw,
                                                 float* __restrict__ vgs) {
    __shared__ float ws_dw[64 * 36];
    __shared__ float gelu_s[64 * 64];
    __shared__ float off_s[2 * 64];
    int n = blockIdx.x;
    int b = n >> 2, g = n & 3;
    int tid = threadIdx.x;
    for (int e = tid; e < 64 * 36; e += 256) ws_dw[e] = wdw[e];
    __syncthreads();
    const float* qn = q + (b * 256 + g * 64) * 1024;
    for (int e = tid; e < 4096; e += 256) {
        int c = e >> 6, pos = e & 63;
        int oy = pos >> 3, ox = pos & 7;
        float acc = bdw[c];
        for (int ky = 0; ky < 6; ky++) {
            int iy = oy * 4 - 1 + ky;
            if (iy < 0 || iy > 31) continue;
            for (int kx = 0; kx < 6; kx++) {
                int ix = ox * 4 - 1 + kx;
                if (ix < 0 || ix > 31) continue;
                acc += qn[c * 1024 + iy * 32 + ix] * ws_dw[c * 36 + ky * 6 + kx];
            }
        }
        gelu_s[c * 64 + pos] = acc * 0.5f * (1.f + erff(acc * 0.70710678118654752f));
    }
    __syncthreads();
    if (tid < 128) {
        int o = tid >> 6, pos = tid & 63;
        float a0 = 0.f, a1 = 0.f;
        for (int c = 0; c < 64; c += 2) {
            a0 += gelu_s[c * 64 + pos] * wpw[o * 64 + c];
            a1 += gelu_s[(c + 1) * 64 + pos] * wpw[o * 64 + c + 1];
        }
        off_s[o * 64 + pos] = tanhf(a0 + a1) * 4.0f;
    }
    __syncthreads();
    if (tid < 64) {
        int oy = tid >> 3, ox = tid & 7;
        float vx = 2.f * ((float)ox + off_s[tid]) / 7.f - 1.f;
        float vy = 2.f * ((float)oy + off_s[64 + tid]) / 7.f - 1.f;
        vgs[(n * 64 + tid) * 2]     = vx;
        vgs[(n * 64 + tid) * 2 + 1] = vy;
    }
}

// ------------- grid_sample (bilinear, zeros, align_corners=F) -------------
__global__ __launch_bounds__(256) void k_sample(const float* __restrict__ x,
                                                const float* __restrict__ vgs,
                                                float* __restrict__ kv) {
    int idx = blockIdx.x * 256 + threadIdx.x;   // 32*64*64
    int pos = idx & 63, c = (idx >> 6) & 63, n = idx >> 12;
    int b = n >> 2, g = n & 3;
    float gx = vgs[(n * 64 + pos) * 2];
    float gy = vgs[(n * 64 + pos) * 2 + 1];
    float ix = (gx + 1.f) * 16.f - 0.5f;
    float iy = (gy + 1.f) * 16.f - 0.5f;
    float x0 = floorf(ix), y0 = floorf(iy);
    float wa = (x0 + 1.f - ix) * (y0 + 1.f - iy);
    float wb = (ix - x0) * (y0 + 1.f - iy);
    float wc = (x0 + 1.f - ix) * (iy - y0);
    float wd = (ix - x0) * (iy - y0);
    const float* img = x + (b * 256 + g * 64 + c) * 1024;
    int xi = (int)x0, yi = (int)y0;
    float acc = 0.f;
    if (xi >= 0 && xi <= 31 && yi >= 0 && yi <= 31)         acc += img[yi * 32 + xi] * wa;
    if (xi + 1 >= 0 && xi + 1 <= 31 && yi >= 0 && yi <= 31) acc += img[yi * 32 + xi + 1] * wb;
    if (xi >= 0 && xi <= 31 && yi + 1 >= 0 && yi + 1 <= 31) acc += img[(yi + 1) * 32 + xi] * wc;
    if (xi + 1 >= 0 && xi + 1 <= 31 && yi + 1 >= 0 && yi + 1 <= 31) acc += img[(yi + 1) * 32 + xi + 1] * wd;
    kv[(n * 64 + c) * 64 + pos] = acc;
}

// ---------------- k,v projection: per (b,g) two 64x64 @ 64x64 -------------
__global__ __launch_bounds__(256) void k_kvproj(const float* __restrict__ kv,
                                                const float* __restrict__ wk,
                                                const float* __restrict__ wv,
                                                float* __restrict__ ko,
                                                float* __restrict__ vo) {
    __shared__ float kvs[4096];
    __shared__ float wkt[4096];
    __shared__ float wvt[4096];
    int n = blockIdx.x, g = n & 3;
    int tid = threadIdx.x;
    for (int e = tid; e < 4096; e += 256) {
        int co = e >> 6, ci = e & 63;
        wkt[ci * 64 + co] = wk[(g * 64 + co) * 64 + ci];
        wvt[ci * 64 + co] = wv[(g * 64 + co) * 64 + ci];
        kvs[e] = kv[n * 4096 + e];
    }
    __syncthreads();
    int cg = tid >> 4, jg = tid & 15;
    int co0 = cg * 4, j0 = jg * 4;
    float ak[4][4] = {}, av[4][4] = {};
    for (int ci = 0; ci < 64; ci++) {
        float4 a1 = *(float4*)&wkt[ci * 64 + co0];
        float4 a2 = *(float4*)&wvt[ci * 64 + co0];
        float4 b4 = *(float4*)&kvs[ci * 64 + j0];
        float w1v[4] = {a1.x, a1.y, a1.z, a1.w};
        float w2v[4] = {a2.x, a2.y, a2.z, a2.w};
        float bb[4] = {b4.x, b4.y, b4.z, b4.w};
        #pragma unroll
        for (int a = 0; a < 4; a++)
            #pragma unroll
            for (int j = 0; j < 4; j++) { ak[a][j] += w1v[a] * bb[j]; av[a][j] += w2v[a] * bb[j]; }
    }
    for (int a = 0; a < 4; a++) {
        float4 o1 = {ak[a][0], ak[a][1], ak[a][2], ak[a][3]};
        float4 o2 = {av[a][0], av[a][1], av[a][2], av[a][3]};
        *(float4*)&ko[n * 4096 + (co0 + a) * 64 + j0] = o1;
        *(float4*)&vo[n * 4096 + (co0 + a) * 64 + j0] = o2;
    }
}

// ------------------- CPB bias MLP (2->64->64->1) via MFMA -----------------
// Layer2 (17 GF) as mfma_f32_16x16x32_bf16: rows = (i,j) pairs, cols = c2.
// Per wave: one i, 64 j rows, 4x4 tile of 16x16 frags, K=64 in 2 steps.
__global__ __launch_bounds__(256) void k_cpb(const float* __restrict__ vgs,
                                             const float* __restrict__ w1,
                                             const float* __restrict__ b1,
                                             const float* __restrict__ w2,
                                             const float* __restrict__ b2,
                                             const float* __restrict__ w3,
                                             const float* __restrict__ b3,
                                             float* __restrict__ bias) {
    __shared__ short w2s[4096];      // [c2][k] bf16 bits, XOR-swizzled 16B slots
    __shared__ float w1s[128];
    __shared__ float b1s[64], b2s[64], w3s[64];
    __shared__ float kxs[64], kys[64];
    int n = blockIdx.y;
    int tid = threadIdx.x;
    for (int e = tid; e < 4096; e += 256) {
        int c2 = e >> 6, k = e & 63;
        int kk = ((k << 1) ^ ((c2 & 7) << 4)) >> 1;   // swizzle byte offset, back to short idx
        __hip_bfloat16 hv = __float2bfloat16(w2[e]);
        w2s[(c2 << 6) + kk] = __builtin_bit_cast(short, hv);
    }
    if (tid < 128) w1s[tid] = w1[tid];
    if (tid < 64) {
        b1s[tid] = b1[tid]; b2s[tid] = b2[tid]; w3s[tid] = w3[tid];
        kxs[tid] = vgs[(n << 7) + tid * 2];
        kys[tid] = vgs[(n << 7) + tid * 2 + 1];
    }
    __syncthreads();

    int wid = tid >> 6, lane = tid & 63;
    int lr = lane & 15, g = lane >> 4;
    float b3v = b3[0];

    // B fragments (W2^T): lane holds B[k][c2], c2 = nt*16+lr, k = s*32 + g*8 + t
    short8b bfrag[4][2];
    #pragma unroll
    for (int nt = 0; nt < 4; nt++) {
        int c2 = nt * 16 + lr;
        #pragma unroll
        for (int s = 0; s < 2; s++) {
            int colb = (s * 64 + g * 16) ^ ((c2 & 7) << 4);
            bfrag[nt][s] = *(short8b*)&w2s[(c2 << 6) + (colb >> 1)];
        }
    }
    // layer-1 weights for this lane's k-set (k depends on g,s,t only)
    float w1a[2][8], w1b[2][8], b1r[2][8];
    #pragma unroll
    for (int s = 0; s < 2; s++)
        #pragma unroll
        for (int t = 0; t < 8; t++) {
            int k = s * 32 + g * 8 + t;
            w1a[s][t] = w1s[2 * k];
            w1b[s][t] = w1s[2 * k + 1];
            b1r[s][t] = b1s[k];
        }
    float b2r[4], w3r[4];
    #pragma unroll
    for (int nt = 0; nt < 4; nt++) { b2r[nt] = b2s[nt * 16 + lr]; w3r[nt] = w3s[nt * 16 + lr]; }

    for (int ii = 0; ii < 4; ii++) {
        int iG = blockIdx.x * 16 + wid * 4 + ii;      // grid.x = 64 -> 1024 i's
        float qx = 2.f * (float)(iG & 31) * (1.f / 31.f) - 1.f;
        float qy = 2.f * (float)(iG >> 5) * (1.f / 31.f) - 1.f;

        // A fragments: h1 rows; row j = m*16 + lr, k = s*32 + g*8 + t
        short8b afrag[4][2];
        #pragma unroll
        for (int m = 0; m < 4; m++) {
            int j = m * 16 + lr;
            float p0 = qx - kxs[j], p1 = qy - kys[j];
            float u0 = copysignf(log1pf(fabsf(p0)), p0);
            float u1 = copysignf(log1pf(fabsf(p1)), p1);
            #pragma unroll
            for (int s = 0; s < 2; s++)
                #pragma unroll
                for (int t = 0; t < 8; t++) {
                    float h = fmaxf(w1a[s][t] * u0 + w1b[s][t] * u1 + b1r[s][t], 0.f);
                    __hip_bfloat16 hb = __float2bfloat16(h);
                    afrag[m][s][t] = __builtin_bit_cast(short, hb);
                }
        }

        f32x4 acc[4][4];
        #pragma unroll
        for (int m = 0; m < 4; m++)
            #pragma unroll
            for (int nt = 0; nt < 4; nt++)
                acc[m][nt] = (f32x4){0.f, 0.f, 0.f, 0.f};
        #pragma unroll
        for (int s = 0; s < 2; s++)
            #pragma unroll
            for (int m = 0; m < 4; m++)
                #pragma unroll
                for (int nt = 0; nt < 4; nt++)
                    acc[m][nt] = __builtin_amdgcn_mfma_f32_16x16x32_bf16(
                        afrag[m][s], bfrag[nt][s], acc[m][nt], 0, 0, 0);

        // layer 3: bias_j = b3 + sum_c2 w3[c2]*relu(D[j][c2]+b2[c2])
        // D layout: col c2 = nt*16+lr, row-in-tile = g*4+r  -> j = m*16+g*4+r
        float red[16];
        #pragma unroll
        for (int m = 0; m < 4; m++)
            #pragma unroll
            for (int r = 0; r < 4; r++) {
                float p = 0.f;
                #pragma unroll
                for (int nt = 0; nt < 4; nt++)
                    p += w3r[nt] * fmaxf(acc[m][nt][r] + b2r[nt], 0.f);
                red[m * 4 + r] = p;
            }
        #pragma unroll
        for (int qq = 0; qq < 16; qq++) {
            red[qq] += __shfl_xor(red[qq], 1);
            red[qq] += __shfl_xor(red[qq], 2);
            red[qq] += __shfl_xor(red[qq], 4);
            red[qq] += __shfl_xor(red[qq], 8);
        }
        // lane (g,lr) writes j = (lr>>2)*16 + g*4 + (lr&3) with value red[lr]
        float v = red[0];
        #pragma unroll
        for (int qq = 1; qq < 16; qq++) v = (lr == qq) ? red[qq] : v;
        int j = (lr >> 2) * 16 + g * 4 + (lr & 3);
        bias[(n * 1024 + iG) * 64 + j] = v + b3v;
    }
}

// --------- fused attention: sim + bias + softmax + PV per (b,h,i64) -------
__global__ __launch_bounds__(256) void k_attn(const float* __restrict__ q,
                                              const float* __restrict__ kk,
                                              const float* __restrict__ vv,
                                              const float* __restrict__ bias,
                                              float* __restrict__ att_out) {
    __shared__ float sm[3 * 4352];
    float* qs = sm;                 // [i*68 + d]
    float* ks = sm + 4352;          // [j*68 + d]
    float* vs = sm + 8704;          // [j*68 + d]
    float* pst = sm;                // overlays qs after sim phase: [j*68 + i]
    int it = blockIdx.x, h = blockIdx.y, b = blockIdx.z;
    int i0 = it * 64;
    int n = b * 4 + h;
    int tid = threadIdx.x;
    for (int e = tid; e < 4096; e += 256) {
        int d = e >> 6, r = e & 63;
        qs[r * 68 + d] = q[(b * 256 + h * 64 + d) * 1024 + i0 + r] * QSCALE;
        ks[r * 68 + d] = kk[n * 4096 + d * 64 + r];
        vs[r * 68 + d] = vv[n * 4096 + d * 64 + r];
    }
    __syncthreads();
    int i = tid >> 2, jq = tid & 3;
    float s[16];
    const float* brow = bias + (n * 1024 + i0 + i) * 64 + jq * 16;
    for (int jj = 0; jj < 16; jj++) {
        int j = jq * 16 + jj;
        float d0 = 0.f, d1 = 0.f, d2 = 0.f, d3 = 0.f;
        #pragma unroll
        for (int dq = 0; dq < 16; dq++) {
            float4 qv = *(float4*)&qs[i * 68 + dq * 4];
            float4 kv4 = *(float4*)&ks[j * 68 + dq * 4];
            d0 += qv.x * kv4.x; d1 += qv.y * kv4.y;
            d2 += qv.z * kv4.z; d3 += qv.w * kv4.w;
        }
        s[jj] = ((d0 + d1) + (d2 + d3)) + brow[jj];
    }
    float m = s[0];
    for (int jj = 1; jj < 16; jj++) m = fmaxf(m, s[jj]);
    m = fmaxf(m, __shfl_xor(m, 1));
    m = fmaxf(m, __shfl_xor(m, 2));
    float sum = 0.f;
    for (int jj = 0; jj < 16; jj++) { s[jj] = expf(s[jj] - m); sum += s[jj]; }
    sum += __shfl_xor(sum, 1);
    sum += __shfl_xor(sum, 2);
    float inv = 1.f / sum;
    __syncthreads();   // everyone done reading qs
    for (int jj = 0; jj < 16; jj++) pst[(jq * 16 + jj) * 68 + i] = s[jj] * inv;
    __syncthreads();
    int ii = tid & 63, dq = tid >> 6;
    float acc[16] = {};
    for (int j = 0; j < 64; j++) {
        float pv = pst[j * 68 + ii];
        float4 v0 = *(float4*)&vs[j * 68 + dq * 16];
        float4 v1 = *(float4*)&vs[j * 68 + dq * 16 + 4];
        float4 v2 = *(float4*)&vs[j * 68 + dq * 16 + 8];
        float4 v3 = *(float4*)&vs[j * 68 + dq * 16 + 12];
        float vvv[16] = {v0.x, v0.y, v0.z, v0.w, v1.x, v1.y, v1.z, v1.w,
                         v2.x, v2.y, v2.z, v2.w, v3.x, v3.y, v3.z, v3.w};
        #pragma unroll
        for (int dd = 0; dd < 16; dd++) acc[dd] += pv * vvv[dd];
    }
    for (int dd = 0; dd < 16; dd++)
        att_out[(b * 256 + h * 64 + dq * 16 + dd) * 1024 + i0 + ii] = acc[dd];
}

// ---------------- output projection: per b 256x256 @ 256x1024 -------------
__global__ __launch_bounds__(256) void k_outproj(const float* __restrict__ att,
                                                 const float* __restrict__ wout,
                                                 const float* __restrict__ bout,
                                                 float* __restrict__ y) {
    __shared__ float Wt[64 * 128];   // [ci][co]
    __shared__ float as[64 * 128];   // [ci][hw]
    int ht = blockIdx.x, ct = blockIdx.y, b = blockIdx.z;
    int tid = threadIdx.x;
    int cg = tid >> 4, hg = tid & 15;
    int co0 = cg * 8, hw0 = hg * 8;
    float acc[8][8] = {};
    for (int kt = 0; kt < 4; kt++) {
        __syncthreads();
        for (int e = tid; e < 8192; e += 256) {
            int co = e >> 6, ci = e & 63;
            Wt[ci * 128 + co] = wout[(ct * 128 + co) * 256 + kt * 64 + ci];
        }
        for (int e = tid; e < 2048; e += 256) {
            int ci = e >> 5, hq = e & 31;
            *(float4*)&as[ci * 128 + hq * 4] =
                *(const float4*)&att[(b * 256 + kt * 64 + ci) * 1024 + ht * 128 + hq * 4];
        }
        __syncthreads();
        for (int ci = 0; ci < 64; ci++) {
            float4 a0 = *(float4*)&Wt[ci * 128 + co0];
            float4 a1 = *(float4*)&Wt[ci * 128 + co0 + 4];
            float4 b0 = *(float4*)&as[ci * 128 + hw0];
            float4 b1 = *(float4*)&as[ci * 128 + hw0 + 4];
            float av[8] = {a0.x, a0.y, a0.z, a0.w, a1.x, a1.y, a1.z, a1.w};
            float bv[8] = {b0.x, b0.y, b0.z, b0.w, b1.x, b1.y, b1.z, b1.w};
            #pragma unroll
            for (int a = 0; a < 8; a++)
                #pragma unroll
                for (int c = 0; c < 8; c++) acc[a][c] += av[a] * bv[c];
        }
    }
    for (int a = 0; a < 8; a++) {
        int co = ct * 128 + co0 + a;
        float bo = bout[co];
        float4 o0 = {acc[a][0] + bo, acc[a][1] + bo, acc[a][2] + bo, acc[a][3] + bo};
        float4 o1 = {acc[a][4] + bo, acc[a][5] + bo, acc[a][6] + bo, acc[a][7] + bo};
        *(float4*)&y[(b * 256 + co) * 1024 + ht * 128 + hw0] = o0;
        *(float4*)&y[(b * 256 + co) * 1024 + ht * 128 + hw0 + 4] = o1;
    }
}

extern "C" void kernel_launch(void* const* d_in, const int* in_sizes, int n_in,
                              void* d_out, int out_size, void* d_ws, size_t ws_size,
                              hipStream_t stream) {
    const float* x    = (const float*)d_in[0];
    const float* wq   = (const float*)d_in[1];
    const float* wk   = (const float*)d_in[2];
    const float* wv   = (const float*)d_in[3];
    const float* wdw  = (const float*)d_in[4];
    const float* bdw  = (const float*)d_in[5];
    const float* wpw  = (const float*)d_in[6];
    const float* cw1  = (const float*)d_in[7];
    const float* cb1  = (const float*)d_in[8];
    const float* cw2  = (const float*)d_in[9];
    const float* cb2  = (const float*)d_in[10];
    const float* cw3  = (const float*)d_in[11];
    const float* cb3  = (const float*)d_in[12];
    const float* wout = (const float*)d_in[13];
    const float* bout = (const float*)d_in[14];
    float* y  = (float*)d_out;
    float* ws = (float*)d_ws;

    float* q    = ws;                    // 2,097,152
    float* att  = ws + 2097152;          // 2,097,152
    float* bias = ws + 4194304;          // 2,097,152
    float* kv   = ws + 6291456;          // 131,072
    float* kbuf = ws + 6422528;          // 131,072
    float* vbuf = ws + 6553600;          // 131,072
    float* vgs  = ws + 6684672;          // 4,096

    k_qproj  <<<dim3(8, 4, 8),  256, 0, stream>>>(x, wq, q);
    k_offsets<<<32,             256, 0, stream>>>(q, wdw, bdw, wpw, vgs);
    k_sample <<<512,            256, 0, stream>>>(x, vgs, kv);
    k_kvproj <<<32,             256, 0, stream>>>(kv, wk, wv, kbuf, vbuf);
    k_cpb    <<<dim3(64, 32),   256, 0, stream>>>(vgs, cw1, cb1, cw2, cb2, cw3, cb3, bias);
    k_attn   <<<dim3(16, 4, 8), 256, 0, stream>>>(q, kbuf, vbuf, bias, att);
    k_outproj<<<dim3(8, 2, 8),  256, 0, stream>>>(att, wout, bout, y);
}

// Round 3
// 187.392 us; speedup vs baseline: 6.4408x; 1.2339x over previous
//
#include <hip/hip_runtime.h>
#include <hip/hip_bf16.h>
#include <math.h>

#define QSCALE 0.125f

typedef __attribute__((ext_vector_type(8))) short short8b;   // 8 bf16 (4 VGPRs)
typedef __attribute__((ext_vector_type(4))) float f32x4;

__device__ __forceinline__ short bf16b(float x) {
    return __builtin_bit_cast(short, __float2bfloat16(x));
}
__device__ __forceinline__ uint pack2(float a, float b) {
    return (uint)(unsigned short)bf16b(a) | ((uint)(unsigned short)bf16b(b) << 16);
}
__device__ __forceinline__ float slogf_(float p) {
    return copysignf(log1pf(fabsf(p)), p);
}

// ---------------- q projection: per (b,g) 64x64 @ 64x1024 ----------------
// writes q f32 [c][hw] (for offsets) and qbt bf16 [bh][i][d] scaled (for attn)
__global__ __launch_bounds__(256) void k_qproj(const float* __restrict__ x,
                                               const float* __restrict__ wq,
                                               float* __restrict__ q,
                                               short* __restrict__ qbt) {
    __shared__ float Wst[64 * 64];   // [ci][co]
    __shared__ float xs[64 * 128];   // [ci][hw]
    int ht = blockIdx.x, g = blockIdx.y, b = blockIdx.z;
    int tid = threadIdx.x;
    for (int e = tid; e < 4096; e += 256) {
        int co = e >> 6, ci = e & 63;
        Wst[ci * 64 + co] = wq[(g * 64 + co) * 64 + ci];
    }
    const float* xb = x + (b * 256 + g * 64) * 1024 + ht * 128;
    for (int e = tid; e < 2048; e += 256) {
        int ci = e >> 5, hq = e & 31;
        *(float4*)&xs[ci * 128 + hq * 4] = *(const float4*)&xb[ci * 1024 + hq * 4];
    }
    __syncthreads();
    int cg = tid >> 4, hg = tid & 15;
    int co0 = cg * 4, hw0 = hg * 8;
    float acc[4][8];
    for (int a = 0; a < 4; a++) for (int c = 0; c < 8; c++) acc[a][c] = 0.f;
    for (int ci = 0; ci < 64; ci++) {
        float4 a4 = *(float4*)&Wst[ci * 64 + co0];
        float4 b0 = *(float4*)&xs[ci * 128 + hw0];
        float4 b1 = *(float4*)&xs[ci * 128 + hw0 + 4];
        float av[4] = {a4.x, a4.y, a4.z, a4.w};
        float bv[8] = {b0.x, b0.y, b0.z, b0.w, b1.x, b1.y, b1.z, b1.w};
        #pragma unroll
        for (int a = 0; a < 4; a++)
            #pragma unroll
            for (int c = 0; c < 8; c++) acc[a][c] += av[a] * bv[c];
    }
    float* qb = q + (b * 256 + g * 64) * 1024 + ht * 128;
    for (int a = 0; a < 4; a++) {
        float4 o0 = {acc[a][0], acc[a][1], acc[a][2], acc[a][3]};
        float4 o1 = {acc[a][4], acc[a][5], acc[a][6], acc[a][7]};
        *(float4*)&qb[(co0 + a) * 1024 + hw0] = o0;
        *(float4*)&qb[(co0 + a) * 1024 + hw0 + 4] = o1;
    }
    // bf16 scaled transposed copy for attention: qbt[(b*4+g)*1024 + i][d]
    short* q16 = qbt + ((size_t)((b * 4 + g) * 1024 + ht * 128)) * 64;
    for (int c = 0; c < 8; c++) {
        int i = hw0 + c;
        uint2 uu;
        uu.x = pack2(acc[0][c] * QSCALE, acc[1][c] * QSCALE);
        uu.y = pack2(acc[2][c] * QSCALE, acc[3][c] * QSCALE);
        *(uint2*)&q16[i * 64 + co0] = uu;
    }
}

// --------- offsets: dwconv6x6 s4 p1 + GELU + 1x1 + tanh*4 -> vgs ---------
__global__ __launch_bounds__(256) void k_offsets(const float* __restrict__ q,
                                                 const float* __restrict__ wdw,
                                                 const float* __restrict__ bdw,
                                                 const float* __restrict__ wpw,
                                                 float* __restrict__ vgs) {
    __shared__ float ws_dw[64 * 36];
    __shared__ float gelu_s[64 * 64];
    __shared__ float off_s[2 * 64];
    int n = blockIdx.x;
    int b = n >> 2, g = n & 3;
    int tid = threadIdx.x;
    for (int e = tid; e < 64 * 36; e += 256) ws_dw[e] = wdw[e];
    __syncthreads();
    const float* qn = q + (b * 256 + g * 64) * 1024;
    for (int e = tid; e < 4096; e += 256) {
        int c = e >> 6, pos = e & 63;
        int oy = pos >> 3, ox = pos & 7;
        float acc = bdw[c];
        for (int ky = 0; ky < 6; ky++) {
            int iy = oy * 4 - 1 + ky;
            if (iy < 0 || iy > 31) continue;
            for (int kx = 0; kx < 6; kx++) {
                int ix = ox * 4 - 1 + kx;
                if (ix < 0 || ix > 31) continue;
                acc += qn[c * 1024 + iy * 32 + ix] * ws_dw[c * 36 + ky * 6 + kx];
            }
        }
        gelu_s[c * 64 + pos] = acc * 0.5f * (1.f + erff(acc * 0.70710678118654752f));
    }
    __syncthreads();
    if (tid < 128) {
        int o = tid >> 6, pos = tid & 63;
        float a0 = 0.f, a1 = 0.f;
        for (int c = 0; c < 64; c += 2) {
            a0 += gelu_s[c * 64 + pos] * wpw[o * 64 + c];
            a1 += gelu_s[(c + 1) * 64 + pos] * wpw[o * 64 + c + 1];
        }
        off_s[o * 64 + pos] = tanhf(a0 + a1) * 4.0f;
    }
    __syncthreads();
    if (tid < 64) {
        int oy = tid >> 3, ox = tid & 7;
        float vx = 2.f * ((float)ox + off_s[tid]) / 7.f - 1.f;
        float vy = 2.f * ((float)oy + off_s[64 + tid]) / 7.f - 1.f;
        vgs[(n * 64 + tid) * 2]     = vx;
        vgs[(n * 64 + tid) * 2 + 1] = vy;
    }
}

// ------------- grid_sample (bilinear, zeros, align_corners=F) -------------
__global__ __launch_bounds__(256) void k_sample(const float* __restrict__ x,
                                                const float* __restrict__ vgs,
                                                float* __restrict__ kv) {
    int idx = blockIdx.x * 256 + threadIdx.x;   // 32*64*64
    int pos = idx & 63, c = (idx >> 6) & 63, n = idx >> 12;
    int b = n >> 2, g = n & 3;
    float gx = vgs[(n * 64 + pos) * 2];
    float gy = vgs[(n * 64 + pos) * 2 + 1];
    float ix = (gx + 1.f) * 16.f - 0.5f;
    float iy = (gy + 1.f) * 16.f - 0.5f;
    float x0 = floorf(ix), y0 = floorf(iy);
    float wa = (x0 + 1.f - ix) * (y0 + 1.f - iy);
    float wb = (ix - x0) * (y0 + 1.f - iy);
    float wc = (x0 + 1.f - ix) * (iy - y0);
    float wd = (ix - x0) * (iy - y0);
    const float* img = x + (b * 256 + g * 64 + c) * 1024;
    int xi = (int)x0, yi = (int)y0;
    float acc = 0.f;
    if (xi >= 0 && xi <= 31 && yi >= 0 && yi <= 31)         acc += img[yi * 32 + xi] * wa;
    if (xi + 1 >= 0 && xi + 1 <= 31 && yi >= 0 && yi <= 31) acc += img[yi * 32 + xi + 1] * wb;
    if (xi >= 0 && xi <= 31 && yi + 1 >= 0 && yi + 1 <= 31) acc += img[(yi + 1) * 32 + xi] * wc;
    if (xi + 1 >= 0 && xi + 1 <= 31 && yi + 1 >= 0 && yi + 1 <= 31) acc += img[(yi + 1) * 32 + xi + 1] * wd;
    kv[(n * 64 + c) * 64 + pos] = acc;
}

// -------- k,v projection: per (b,g) two 64x64 @ 64x64 -> bf16 out ---------
// kob bf16 [n][j][d]   (K row-major for sim B-frags)
// vob bf16 [n][d][j]   (V col-major for PV B-frags)
__global__ __launch_bounds__(256) void k_kvproj(const float* __restrict__ kv,
                                                const float* __restrict__ wk,
                                                const float* __restrict__ wv,
                                                short* __restrict__ kob,
                                                short* __restrict__ vob) {
    __shared__ float kvs[4096];
    __shared__ float wkt[4096];
    __shared__ float wvt[4096];
    int n = blockIdx.x, g = n & 3;
    int tid = threadIdx.x;
    for (int e = tid; e < 4096; e += 256) {
        int co = e >> 6, ci = e & 63;
        wkt[ci * 64 + co] = wk[(g * 64 + co) * 64 + ci];
        wvt[ci * 64 + co] = wv[(g * 64 + co) * 64 + ci];
        kvs[e] = kv[n * 4096 + e];
    }
    __syncthreads();
    int cg = tid >> 4, jg = tid & 15;
    int co0 = cg * 4, j0 = jg * 4;
    float ak[4][4] = {}, av[4][4] = {};
    for (int ci = 0; ci < 64; ci++) {
        float4 a1 = *(float4*)&wkt[ci * 64 + co0];
        float4 a2 = *(float4*)&wvt[ci * 64 + co0];
        float4 b4 = *(float4*)&kvs[ci * 64 + j0];
        float w1v[4] = {a1.x, a1.y, a1.z, a1.w};
        float w2v[4] = {a2.x, a2.y, a2.z, a2.w};
        float bb[4] = {b4.x, b4.y, b4.z, b4.w};
        #pragma unroll
        for (int a = 0; a < 4; a++)
            #pragma unroll
            for (int j = 0; j < 4; j++) { ak[a][j] += w1v[a] * bb[j]; av[a][j] += w2v[a] * bb[j]; }
    }
    for (int jj = 0; jj < 4; jj++) {
        uint2 uu;
        uu.x = pack2(ak[0][jj], ak[1][jj]);
        uu.y = pack2(ak[2][jj], ak[3][jj]);
        *(uint2*)&kob[n * 4096 + (j0 + jj) * 64 + co0] = uu;
    }
    for (int a = 0; a < 4; a++) {
        uint2 uu;
        uu.x = pack2(av[a][0], av[a][1]);
        uu.y = pack2(av[a][2], av[a][3]);
        *(uint2*)&vob[n * 4096 + (co0 + a) * 64 + j0] = uu;
    }
}

// ------------------- CPB bias MLP (2->64->64->1) via MFMA -----------------
// Layer1 hoisted to tables (iy const per block, ix spans 16), layer2 MFMA,
// layer3 via per-wave LDS scratch transpose.
__global__ __launch_bounds__(256) void k_cpb(const float* __restrict__ vgs,
                                             const float* __restrict__ w1,
                                             const float* __restrict__ b1,
                                             const float* __restrict__ w2,
                                             const float* __restrict__ b2,
                                             const float* __restrict__ w3,
                                             const float* __restrict__ b3,
                                             float* __restrict__ bias) {
    __shared__ short w2s[4096];          // [c2][k] bf16 bits, XOR-swizzled 16B slots
    __shared__ float Q1s[64 * 68];       // [j][k] = w1b[k]*u1[j] + b1[k]
    __shared__ float u0s[16 * 64];       // [l][j] = slog(qx(l) - kx[j])
    __shared__ float u1s[64], kxs_[64], w1as[64], b2s_[64], w3s_[64];
    __shared__ float scr[4][64 * 20];    // per-wave layer3 transpose scratch
    int it = blockIdx.x, n = blockIdx.y, tid = threadIdx.x;
    int xb = (it & 1) * 16;
    float qy = 2.f * (float)(it >> 1) / 31.f - 1.f;

    for (int e = tid; e < 4096; e += 256) {
        int c2 = e >> 6, k = e & 63;
        int kk = ((k << 1) ^ ((c2 & 7) << 4)) >> 1;
        w2s[(c2 << 6) + kk] = bf16b(w2[e]);
    }
    if (tid < 64) {
        float kx = vgs[(n << 7) + tid * 2], ky = vgs[(n << 7) + tid * 2 + 1];
        kxs_[tid] = kx;
        u1s[tid] = slogf_(qy - ky);
        w1as[tid] = w1[2 * tid];
        b2s_[tid] = b2[tid];
        w3s_[tid] = w3[tid];
    }
    __syncthreads();
    for (int e = tid; e < 4096; e += 256) {
        int j = e >> 6, k = e & 63;
        Q1s[j * 68 + k] = fmaf(w1[2 * k + 1], u1s[j], b1[k]);
    }
    for (int e = tid; e < 1024; e += 256) {
        int l = e >> 6, j = e & 63;
        float qx = (2.f / 31.f) * (float)(xb + l) - 1.f;
        u0s[e] = slogf_(qx - kxs_[j]);
    }
    __syncthreads();

    int wid = tid >> 6, lane = tid & 63, lr = lane & 15, g = lane >> 4;
    float b3v = b3[0];

    short8b bfrag[4][2];
    #pragma unroll
    for (int nt = 0; nt < 4; nt++) {
        int c2 = nt * 16 + lr;
        #pragma unroll
        for (int s = 0; s < 2; s++) {
            int colb = (s * 64 + g * 16) ^ ((c2 & 7) << 4);
            bfrag[nt][s] = *(short8b*)&w2s[(c2 << 6) + (colb >> 1)];
        }
    }
    float4 w1r[2][2];
    w1r[0][0] = *(float4*)&w1as[g * 8];
    w1r[0][1] = *(float4*)&w1as[g * 8 + 4];
    w1r[1][0] = *(float4*)&w1as[32 + g * 8];
    w1r[1][1] = *(float4*)&w1as[32 + g * 8 + 4];
    float b2r[4], w3r[4];
    #pragma unroll
    for (int nt = 0; nt < 4; nt++) { b2r[nt] = b2s_[nt * 16 + lr]; w3r[nt] = w3s_[nt * 16 + lr]; }
    float* myscr = scr[wid];

    for (int ii = 0; ii < 4; ii++) {
        int il = wid * 4 + ii;
        int iG = it * 16 + il;

        short8b afrag[4][2];
        #pragma unroll
        for (int m = 0; m < 4; m++) {
            float u0v = u0s[il * 64 + m * 16 + lr];
            const float* q1p = &Q1s[(m * 16 + lr) * 68];
            #pragma unroll
            for (int s = 0; s < 2; s++) {
                float4 qa = *(float4*)&q1p[s * 32 + g * 8];
                float4 qb4 = *(float4*)&q1p[s * 32 + g * 8 + 4];
                short8b af;
                af[0] = bf16b(fmaxf(fmaf(w1r[s][0].x, u0v, qa.x), 0.f));
                af[1] = bf16b(fmaxf(fmaf(w1r[s][0].y, u0v, qa.y), 0.f));
                af[2] = bf16b(fmaxf(fmaf(w1r[s][0].z, u0v, qa.z), 0.f));
                af[3] = bf16b(fmaxf(fmaf(w1r[s][0].w, u0v, qa.w), 0.f));
                af[4] = bf16b(fmaxf(fmaf(w1r[s][1].x, u0v, qb4.x), 0.f));
                af[5] = bf16b(fmaxf(fmaf(w1r[s][1].y, u0v, qb4.y), 0.f));
                af[6] = bf16b(fmaxf(fmaf(w1r[s][1].z, u0v, qb4.z), 0.f));
                af[7] = bf16b(fmaxf(fmaf(w1r[s][1].w, u0v, qb4.w), 0.f));
                afrag[m][s] = af;
            }
        }

        f32x4 acc[4][4];
        #pragma unroll
        for (int m = 0; m < 4; m++)
            #pragma unroll
            for (int nt = 0; nt < 4; nt++)
                acc[m][nt] = (f32x4){0.f, 0.f, 0.f, 0.f};
        #pragma unroll
        for (int s = 0; s < 2; s++)
            #pragma unroll
            for (int m = 0; m < 4; m++)
                #pragma unroll
                for (int nt = 0; nt < 4; nt++)
                    acc[m][nt] = __builtin_amdgcn_mfma_f32_16x16x32_bf16(
                        afrag[m][s], bfrag[nt][s], acc[m][nt], 0, 0, 0);

        // layer 3 partials -> scratch [j][lr]
        #pragma unroll
        for (int m = 0; m < 4; m++)
            #pragma unroll
            for (int r = 0; r < 4; r++) {
                float p = 0.f;
                #pragma unroll
                for (int nt = 0; nt < 4; nt++)
                    p += w3r[nt] * fmaxf(acc[m][nt][r] + b2r[nt], 0.f);
                myscr[(m * 16 + g * 4 + r) * 20 + lr] = p;
            }
        // reduce: lane j sums its 16 partials
        float4 v0 = *(float4*)&myscr[lane * 20];
        float4 v1 = *(float4*)&myscr[lane * 20 + 4];
        float4 v2 = *(float4*)&myscr[lane * 20 + 8];
        float4 v3 = *(float4*)&myscr[lane * 20 + 12];
        float ssum = ((v0.x + v0.y) + (v0.z + v0.w)) + ((v1.x + v1.y) + (v1.z + v1.w))
                   + ((v2.x + v2.y) + (v2.z + v2.w)) + ((v3.x + v3.y) + (v3.z + v3.w));
        bias[((size_t)n * 1024 + iG) * 64 + lane] = ssum + b3v;
    }
}

// --------- fused attention via MFMA: per wave 16 i x 64 j, no barriers -----
__global__ __launch_bounds__(256) void k_attn(const short* __restrict__ qbt,
                                              const short* __restrict__ kob,
                                              const short* __restrict__ vob,
                                              const float* __restrict__ bias,
                                              float* __restrict__ att) {
    __shared__ float scr[4][1088];   // per-wave: P [16][68] then outT [64][17]
    int it = blockIdx.x, h = blockIdx.y, b = blockIdx.z;
    int n = b * 4 + h;
    int tid = threadIdx.x, wid = tid >> 6, lane = tid & 63, lr = lane & 15, g = lane >> 4;
    int i0w = it * 64 + wid * 16;
    float* P = scr[wid];

    // K B-frags: col j = nt*16+lr, k = d = s*32+g*8+t
    const short* kb = kob + n * 4096;
    short8b kf[4][2];
    #pragma unroll
    for (int nt = 0; nt < 4; nt++)
        #pragma unroll
        for (int s = 0; s < 2; s++)
            kf[nt][s] = *(const short8b*)&kb[(nt * 16 + lr) * 64 + s * 32 + g * 8];
    // V B-frags: col d = nt*16+lr, k = j = s*32+g*8+t
    const short* vb = vob + n * 4096;
    short8b vf[4][2];
    #pragma unroll
    for (int nt = 0; nt < 4; nt++)
        #pragma unroll
        for (int s = 0; s < 2; s++)
            vf[nt][s] = *(const short8b*)&vb[(nt * 16 + lr) * 64 + s * 32 + g * 8];
    // Q A-frag: row i = lr, k = d
    const short* qb = qbt + ((size_t)n * 1024 + i0w + lr) * 64;
    short8b qf[2];
    qf[0] = *(const short8b*)&qb[g * 8];
    qf[1] = *(const short8b*)&qb[32 + g * 8];
    // bias
    float bv[4][4];
    #pragma unroll
    for (int r = 0; r < 4; r++)
        #pragma unroll
        for (int nt = 0; nt < 4; nt++)
            bv[r][nt] = bias[((size_t)n * 1024 + i0w + g * 4 + r) * 64 + nt * 16 + lr];

    // sim = Q K^T
    f32x4 acc[4];
    #pragma unroll
    for (int nt = 0; nt < 4; nt++) acc[nt] = (f32x4){0.f, 0.f, 0.f, 0.f};
    #pragma unroll
    for (int s = 0; s < 2; s++)
        #pragma unroll
        for (int nt = 0; nt < 4; nt++)
            acc[nt] = __builtin_amdgcn_mfma_f32_16x16x32_bf16(qf[s], kf[nt][s], acc[nt], 0, 0, 0);

    // softmax per row (i = g*4+r), cols split over lr(16) x nt(4)
    #pragma unroll
    for (int r = 0; r < 4; r++) {
        float s0 = acc[0][r] + bv[r][0], s1 = acc[1][r] + bv[r][1];
        float s2 = acc[2][r] + bv[r][2], s3 = acc[3][r] + bv[r][3];
        float m = fmaxf(fmaxf(s0, s1), fmaxf(s2, s3));
        m = fmaxf(m, __shfl_xor(m, 1));
        m = fmaxf(m, __shfl_xor(m, 2));
        m = fmaxf(m, __shfl_xor(m, 4));
        m = fmaxf(m, __shfl_xor(m, 8));
        float e0 = __expf(s0 - m), e1 = __expf(s1 - m);
        float e2 = __expf(s2 - m), e3 = __expf(s3 - m);
        float sum = (e0 + e1) + (e2 + e3);
        sum += __shfl_xor(sum, 1);
        sum += __shfl_xor(sum, 2);
        sum += __shfl_xor(sum, 4);
        sum += __shfl_xor(sum, 8);
        float inv = 1.f / sum;
        int row = g * 4 + r;
        P[row * 68 + lr]      = e0 * inv;
        P[row * 68 + 16 + lr] = e1 * inv;
        P[row * 68 + 32 + lr] = e2 * inv;
        P[row * 68 + 48 + lr] = e3 * inv;
    }

    // PV: A = P (row i = lr, k = j), B = V
    const float* pr = &P[lr * 68];
    float4 a0 = *(float4*)&pr[g * 8];
    float4 a1 = *(float4*)&pr[g * 8 + 4];
    float4 a2 = *(float4*)&pr[32 + g * 8];
    float4 a3 = *(float4*)&pr[32 + g * 8 + 4];
    short8b pf0, pf1;
    pf0[0] = bf16b(a0.x); pf0[1] = bf16b(a0.y); pf0[2] = bf16b(a0.z); pf0[3] = bf16b(a0.w);
    pf0[4] = bf16b(a1.x); pf0[5] = bf16b(a1.y); pf0[6] = bf16b(a1.z); pf0[7] = bf16b(a1.w);
    pf1[0] = bf16b(a2.x); pf1[1] = bf16b(a2.y); pf1[2] = bf16b(a2.z); pf1[3] = bf16b(a2.w);
    pf1[4] = bf16b(a3.x); pf1[5] = bf16b(a3.y); pf1[6] = bf16b(a3.z); pf1[7] = bf16b(a3.w);

    f32x4 oacc[4];
    #pragma unroll
    for (int nt = 0; nt < 4; nt++) oacc[nt] = (f32x4){0.f, 0.f, 0.f, 0.f};
    #pragma unroll
    for (int nt = 0; nt < 4; nt++) {
        oacc[nt] = __builtin_amdgcn_mfma_f32_16x16x32_bf16(pf0, vf[nt][0], oacc[nt], 0, 0, 0);
        oacc[nt] = __builtin_amdgcn_mfma_f32_16x16x32_bf16(pf1, vf[nt][1], oacc[nt], 0, 0, 0);
    }

    // transpose out tile via scratch: [d][i16], then coalesced 64B-line stores
    #pragma unroll
    for (int nt = 0; nt < 4; nt++)
        #pragma unroll
        for (int r = 0; r < 4; r++)
            P[(nt * 16 + lr) * 17 + g * 4 + r] = oacc[nt][r];
    float o[16];
    #pragma unroll
    for (int c = 0; c < 16; c++) o[c] = P[lane * 17 + c];
    float* ap = att + ((size_t)(b * 256 + h * 64 + lane)) * 1024 + i0w;
    float4 w0 = {o[0], o[1], o[2], o[3]};
    float4 w1 = {o[4], o[5], o[6], o[7]};
    float4 w2 = {o[8], o[9], o[10], o[11]};
    float4 w3 = {o[12], o[13], o[14], o[15]};
    *(float4*)&ap[0]  = w0;
    *(float4*)&ap[4]  = w1;
    *(float4*)&ap[8]  = w2;
    *(float4*)&ap[12] = w3;
}

// ---------------- output projection: per b 256x256 @ 256x1024 -------------
__global__ __launch_bounds__(256) void k_outproj(const float* __restrict__ att,
                                                 const float* __restrict__ wout,
                                                 const float* __restrict__ bout,
                                                 float* __restrict__ y) {
    __shared__ float Wt[64 * 128];   // [ci][co]
    __shared__ float as[64 * 128];   // [ci][hw]
    int ht = blockIdx.x, ct = blockIdx.y, b = blockIdx.z;
    int tid = threadIdx.x;
    int cg = tid >> 4, hg = tid & 15;
    int co0 = cg * 8, hw0 = hg * 8;
    float acc[8][8] = {};
    for (int kt = 0; kt < 4; kt++) {
        __syncthreads();
        for (int e = tid; e < 8192; e += 256) {
            int co = e >> 6, ci = e & 63;
            Wt[ci * 128 + co] = wout[(ct * 128 + co) * 256 + kt * 64 + ci];
        }
        for (int e = tid; e < 2048; e += 256) {
            int ci = e >> 5, hq = e & 31;
            *(float4*)&as[ci * 128 + hq * 4] =
                *(const float4*)&att[(b * 256 + kt * 64 + ci) * 1024 + ht * 128 + hq * 4];
        }
        __syncthreads();
        for (int ci = 0; ci < 64; ci++) {
            float4 a0 = *(float4*)&Wt[ci * 128 + co0];
            float4 a1 = *(float4*)&Wt[ci * 128 + co0 + 4];
            float4 b0 = *(float4*)&as[ci * 128 + hw0];
            float4 b1 = *(float4*)&as[ci * 128 + hw0 + 4];
            float av[8] = {a0.x, a0.y, a0.z, a0.w, a1.x, a1.y, a1.z, a1.w};
            float bv[8] = {b0.x, b0.y, b0.z, b0.w, b1.x, b1.y, b1.z, b1.w};
            #pragma unroll
            for (int a = 0; a < 8; a++)
                #pragma unroll
                for (int c = 0; c < 8; c++) acc[a][c] += av[a] * bv[c];
        }
    }
    for (int a = 0; a < 8; a++) {
        int co = ct * 128 + co0 + a;
        float bo = bout[co];
        float4 o0 = {acc[a][0] + bo, acc[a][1] + bo, acc[a][2] + bo, acc[a][3] + bo};
        float4 o1 = {acc[a][4] + bo, acc[a][5] + bo, acc[a][6] + bo, acc[a][7] + bo};
        *(float4*)&y[(b * 256 + co) * 1024 + ht * 128 + hw0] = o0;
        *(float4*)&y[(b * 256 + co) * 1024 + ht * 128 + hw0 + 4] = o1;
    }
}

extern "C" void kernel_launch(void* const* d_in, const int* in_sizes, int n_in,
                              void* d_out, int out_size, void* d_ws, size_t ws_size,
                              hipStream_t stream) {
    const float* x    = (const float*)d_in[0];
    const float* wq   = (const float*)d_in[1];
    const float* wk   = (const float*)d_in[2];
    const float* wv   = (const float*)d_in[3];
    const float* wdw  = (const float*)d_in[4];
    const float* bdw  = (const float*)d_in[5];
    const float* wpw  = (const float*)d_in[6];
    const float* cw1  = (const float*)d_in[7];
    const float* cb1  = (const float*)d_in[8];
    const float* cw2  = (const float*)d_in[9];
    const float* cb2  = (const float*)d_in[10];
    const float* cw3  = (const float*)d_in[11];
    const float* cb3  = (const float*)d_in[12];
    const float* wout = (const float*)d_in[13];
    const float* bout = (const float*)d_in[14];
    float* y  = (float*)d_out;
    float* ws = (float*)d_ws;

    float* q    = ws;                          // 2,097,152 f32 (dead after k_offsets)
    float* att  = ws;                          // alias: attn output reuses q region
    float* bias = ws + 2097152;                // 2,097,152 f32
    float* kv   = ws + 4194304;                // 131,072 f32
    float* vgs  = ws + 4325376;                // 4,096 f32
    short* qbt  = (short*)(ws + 4329472);      // 2,097,152 bf16
    short* kob  = (short*)(ws + 5378048);      // 131,072 bf16
    short* vob  = (short*)(ws + 5443584);      // 131,072 bf16

    k_qproj  <<<dim3(8, 4, 8),  256, 0, stream>>>(x, wq, q, qbt);
    k_offsets<<<32,             256, 0, stream>>>(q, wdw, bdw, wpw, vgs);
    k_sample <<<512,            256, 0, stream>>>(x, vgs, kv);
    k_kvproj <<<32,             256, 0, stream>>>(kv, wk, wv, kob, vob);
    k_cpb    <<<dim3(64, 32),   256, 0, stream>>>(vgs, cw1, cb1, cw2, cb2, cw3, cb3, bias);
    k_attn   <<<dim3(16, 4, 8), 256, 0, stream>>>(qbt, kob, vob, bias, att);
    k_outproj<<<dim3(8, 2, 8),  256, 0, stream>>>(att, wout, bout, y);
}

// Round 5
// 148.673 us; speedup vs baseline: 8.1182x; 1.2604x over previous
//
#include <hip/hip_runtime.h>
#include <hip/hip_bf16.h>
#include <math.h>

#define QSCALE 0.125f

typedef __attribute__((ext_vector_type(8))) short short8b;   // 8 bf16 (4 VGPRs)
typedef __attribute__((ext_vector_type(4))) float f32x4;

__device__ __forceinline__ short bf16b(float x) {
    return __builtin_bit_cast(short, __float2bfloat16(x));
}
__device__ __forceinline__ uint pack2(float a, float b) {
    return (uint)(unsigned short)bf16b(a) | ((uint)(unsigned short)bf16b(b) << 16);
}
__device__ __forceinline__ float slogf_(float p) {
    return copysignf(log1pf(fabsf(p)), p);
}

// ---------------- q projection: per (b,g) 64x64 @ 64x1024 ----------------
// writes q f32 [c][hw] (for offsets) and qbt bf16 [bh][i][d] scaled (for attn)
__global__ __launch_bounds__(256) void k_qproj(const float* __restrict__ x,
                                               const float* __restrict__ wq,
                                               float* __restrict__ q,
                                               short* __restrict__ qbt) {
    __shared__ float Wst[64 * 64];   // [ci][co]
    __shared__ float xs[64 * 128];   // [ci][hw]
    int ht = blockIdx.x, g = blockIdx.y, b = blockIdx.z;
    int tid = threadIdx.x;
    for (int e = tid; e < 4096; e += 256) {
        int co = e >> 6, ci = e & 63;
        Wst[ci * 64 + co] = wq[(g * 64 + co) * 64 + ci];
    }
    const float* xb = x + (b * 256 + g * 64) * 1024 + ht * 128;
    for (int e = tid; e < 2048; e += 256) {
        int ci = e >> 5, hq = e & 31;
        *(float4*)&xs[ci * 128 + hq * 4] = *(const float4*)&xb[ci * 1024 + hq * 4];
    }
    __syncthreads();
    int cg = tid >> 4, hg = tid & 15;
    int co0 = cg * 4, hw0 = hg * 8;
    float acc[4][8];
    for (int a = 0; a < 4; a++) for (int c = 0; c < 8; c++) acc[a][c] = 0.f;
    for (int ci = 0; ci < 64; ci++) {
        float4 a4 = *(float4*)&Wst[ci * 64 + co0];
        float4 b0 = *(float4*)&xs[ci * 128 + hw0];
        float4 b1 = *(float4*)&xs[ci * 128 + hw0 + 4];
        float av[4] = {a4.x, a4.y, a4.z, a4.w};
        float bv[8] = {b0.x, b0.y, b0.z, b0.w, b1.x, b1.y, b1.z, b1.w};
        #pragma unroll
        for (int a = 0; a < 4; a++)
            #pragma unroll
            for (int c = 0; c < 8; c++) acc[a][c] += av[a] * bv[c];
    }
    float* qb = q + (b * 256 + g * 64) * 1024 + ht * 128;
    for (int a = 0; a < 4; a++) {
        float4 o0 = {acc[a][0], acc[a][1], acc[a][2], acc[a][3]};
        float4 o1 = {acc[a][4], acc[a][5], acc[a][6], acc[a][7]};
        *(float4*)&qb[(co0 + a) * 1024 + hw0] = o0;
        *(float4*)&qb[(co0 + a) * 1024 + hw0 + 4] = o1;
    }
    // bf16 scaled transposed copy for attention: qbt[(b*4+g)*1024 + i][d]
    short* q16 = qbt + ((size_t)((b * 4 + g) * 1024 + ht * 128)) * 64;
    for (int c = 0; c < 8; c++) {
        int i = hw0 + c;
        uint2 uu;
        uu.x = pack2(acc[0][c] * QSCALE, acc[1][c] * QSCALE);
        uu.y = pack2(acc[2][c] * QSCALE, acc[3][c] * QSCALE);
        *(uint2*)&q16[i * 64 + co0] = uu;
    }
}

// --------- offsets stage 1: depthwise conv6x6 s4 p1 + GELU ---------------
// grid (8 cgroups, 32 n); 8 channels per block, q slice staged in LDS.
__global__ __launch_bounds__(256) void k_dw(const float* __restrict__ q,
                                            const float* __restrict__ wdw,
                                            const float* __restrict__ bdw,
                                            float* __restrict__ gdw) {
    __shared__ float qs[8 * 1024];   // 32 KB: [c][iy*32+ix]
    __shared__ float wds[8 * 36];
    int cg = blockIdx.x, n = blockIdx.y;
    int b = n >> 2, gg = n & 3;
    int c0 = cg * 8;
    int tid = threadIdx.x;
    const float* qn = q + (b * 256 + gg * 64 + c0) * 1024;
    for (int e = tid; e < 2048; e += 256)
        ((float4*)qs)[e] = ((const float4*)qn)[e];
    for (int e = tid; e < 288; e += 256)     // FIX: was `if (tid < 288)` with 256 threads
        wds[e] = wdw[c0 * 36 + e];
    __syncthreads();
    for (int e = tid; e < 512; e += 256) {
        int c = e >> 6, pos = e & 63;
        int oy = pos >> 3, ox = pos & 7;
        float acc = bdw[c0 + c];
        #pragma unroll
        for (int ky = 0; ky < 6; ky++) {
            int iy = oy * 4 - 1 + ky;
            if (iy < 0 || iy > 31) continue;
            #pragma unroll
            for (int kx = 0; kx < 6; kx++) {
                int ix = ox * 4 - 1 + kx;
                if (ix < 0 || ix > 31) continue;
                acc += qs[c * 1024 + iy * 32 + ix] * wds[c * 36 + ky * 6 + kx];
            }
        }
        gdw[(n * 64 + c0 + c) * 64 + pos] = acc * 0.5f * (1.f + erff(acc * 0.70710678118654752f));
    }
}

// --------- offsets stage 2: 1x1 conv + tanh*4 -> normalized grid ----------
__global__ __launch_bounds__(64) void k_pw(const float* __restrict__ gdw,
                                           const float* __restrict__ wpw,
                                           float* __restrict__ vgs) {
    int n = blockIdx.x, pos = threadIdx.x;
    const float* gp = gdw + n * 4096 + pos;
    float a0 = 0.f, a1 = 0.f;
    #pragma unroll 8
    for (int c = 0; c < 64; c++) {
        float v = gp[c * 64];
        a0 += v * wpw[c];
        a1 += v * wpw[64 + c];
    }
    float offx = tanhf(a0) * 4.0f, offy = tanhf(a1) * 4.0f;
    int oy = pos >> 3, ox = pos & 7;
    vgs[(n * 64 + pos) * 2]     = 2.f * ((float)ox + offx) / 7.f - 1.f;
    vgs[(n * 64 + pos) * 2 + 1] = 2.f * ((float)oy + offy) / 7.f - 1.f;
}

// ------------- grid_sample (bilinear, zeros, align_corners=F) -------------
__global__ __launch_bounds__(256) void k_sample(const float* __restrict__ x,
                                                const float* __restrict__ vgs,
                                                float* __restrict__ kv) {
    int idx = blockIdx.x * 256 + threadIdx.x;   // 32*64*64
    int pos = idx & 63, c = (idx >> 6) & 63, n = idx >> 12;
    int b = n >> 2, g = n & 3;
    float gx = vgs[(n * 64 + pos) * 2];
    float gy = vgs[(n * 64 + pos) * 2 + 1];
    float ix = (gx + 1.f) * 16.f - 0.5f;
    float iy = (gy + 1.f) * 16.f - 0.5f;
    float x0 = floorf(ix), y0 = floorf(iy);
    float wa = (x0 + 1.f - ix) * (y0 + 1.f - iy);
    float wb = (ix - x0) * (y0 + 1.f - iy);
    float wc = (x0 + 1.f - ix) * (iy - y0);
    float wd = (ix - x0) * (iy - y0);
    const float* img = x + (b * 256 + g * 64 + c) * 1024;
    int xi = (int)x0, yi = (int)y0;
    float acc = 0.f;
    if (xi >= 0 && xi <= 31 && yi >= 0 && yi <= 31)         acc += img[yi * 32 + xi] * wa;
    if (xi + 1 >= 0 && xi + 1 <= 31 && yi >= 0 && yi <= 31) acc += img[yi * 32 + xi + 1] * wb;
    if (xi >= 0 && xi <= 31 && yi + 1 >= 0 && yi + 1 <= 31) acc += img[(yi + 1) * 32 + xi] * wc;
    if (xi + 1 >= 0 && xi + 1 <= 31 && yi + 1 >= 0 && yi + 1 <= 31) acc += img[(yi + 1) * 32 + xi + 1] * wd;
    kv[(n * 64 + c) * 64 + pos] = acc;
}

// -------- k,v projection: per (b,g) two 64x64 @ 64x64 -> bf16 out ---------
__global__ __launch_bounds__(256) void k_kvproj(const float* __restrict__ kv,
                                                const float* __restrict__ wk,
                                                const float* __restrict__ wv,
                                                short* __restrict__ kob,
                                                short* __restrict__ vob) {
    __shared__ float kvs[4096];
    __shared__ float wkt[4096];
    __shared__ float wvt[4096];
    int n = blockIdx.x, g = n & 3;
    int tid = threadIdx.x;
    for (int e = tid; e < 4096; e += 256) {
        int co = e >> 6, ci = e & 63;
        wkt[ci * 64 + co] = wk[(g * 64 + co) * 64 + ci];
        wvt[ci * 64 + co] = wv[(g * 64 + co) * 64 + ci];
        kvs[e] = kv[n * 4096 + e];
    }
    __syncthreads();
    int cg = tid >> 4, jg = tid & 15;
    int co0 = cg * 4, j0 = jg * 4;
    float ak[4][4] = {}, av[4][4] = {};
    for (int ci = 0; ci < 64; ci++) {
        float4 a1 = *(float4*)&wkt[ci * 64 + co0];
        float4 a2 = *(float4*)&wvt[ci * 64 + co0];
        float4 b4 = *(float4*)&kvs[ci * 64 + j0];
        float w1v[4] = {a1.x, a1.y, a1.z, a1.w};
        float w2v[4] = {a2.x, a2.y, a2.z, a2.w};
        float bb[4] = {b4.x, b4.y, b4.z, b4.w};
        #pragma unroll
        for (int a = 0; a < 4; a++)
            #pragma unroll
            for (int j = 0; j < 4; j++) { ak[a][j] += w1v[a] * bb[j]; av[a][j] += w2v[a] * bb[j]; }
    }
    for (int jj = 0; jj < 4; jj++) {
        uint2 uu;
        uu.x = pack2(ak[0][jj], ak[1][jj]);
        uu.y = pack2(ak[2][jj], ak[3][jj]);
        *(uint2*)&kob[n * 4096 + (j0 + jj) * 64 + co0] = uu;
    }
    for (int a = 0; a < 4; a++) {
        uint2 uu;
        uu.x = pack2(av[a][0], av[a][1]);
        uu.y = pack2(av[a][2], av[a][3]);
        *(uint2*)&vob[n * 4096 + (co0 + a) * 64 + j0] = uu;
    }
}

// ------------------- CPB bias MLP (2->64->64->1) via MFMA -----------------
// Transposed GEMM: rows = c2 (A = W2, constant in registers), cols = j-pairs.
// C-layout gives each lane 16 c2-values for ONE pair -> layer3 is in-register
// relu+fma + 2 shfl_xor. No W2 LDS, no scratch LDS. Grid (32 iy, 32 n).
__global__ __launch_bounds__(256) void k_cpb(const float* __restrict__ vgs,
                                             const float* __restrict__ w1,
                                             const float* __restrict__ b1,
                                             const float* __restrict__ w2,
                                             const float* __restrict__ b2,
                                             const float* __restrict__ w3,
                                             const float* __restrict__ b3,
                                             float* __restrict__ bias) {
    __shared__ float Q1s[64 * 68];   // [j][k] = w1b[k]*u1[j] + b1[k]
    __shared__ float u0s[32 * 64];   // [ix][j] = slog(qx(ix) - kx[j])
    __shared__ float u1t[64];
    int iy = blockIdx.x, n = blockIdx.y, tid = threadIdx.x;
    float qy = 2.f * (float)iy / 31.f - 1.f;

    if (tid < 64) u1t[tid] = slogf_(qy - vgs[(n << 7) + tid * 2 + 1]);
    __syncthreads();
    for (int e = tid; e < 4096; e += 256) {
        int j = e >> 6, k = e & 63;
        Q1s[j * 68 + k] = fmaf(w1[2 * k + 1], u1t[j], b1[k]);
    }
    for (int e = tid; e < 2048; e += 256) {
        int ix = e >> 6, j = e & 63;
        float qx = (2.f / 31.f) * (float)ix - 1.f;
        u0s[e] = slogf_(qx - vgs[(n << 7) + j * 2]);
    }

    int wid = tid >> 6, lane = tid & 63, lr = lane & 15, g = lane >> 4;
    float b3v = b3[0];

    // A = W2 fragments (constant): row c2 = m*16+lr, k = s*32+g*8+t
    short8b w2f[4][2];
    #pragma unroll
    for (int m = 0; m < 4; m++)
        #pragma unroll
        for (int s = 0; s < 2; s++) {
            const float* wp = w2 + (m * 16 + lr) * 64 + s * 32 + g * 8;
            float4 c0 = *(const float4*)wp;
            float4 c1 = *(const float4*)(wp + 4);
            short8b f;
            f[0] = bf16b(c0.x); f[1] = bf16b(c0.y); f[2] = bf16b(c0.z); f[3] = bf16b(c0.w);
            f[4] = bf16b(c1.x); f[5] = bf16b(c1.y); f[6] = bf16b(c1.z); f[7] = bf16b(c1.w);
            w2f[m][s] = f;
        }
    // layer-1 'a' weights for this lane's k-slice
    float w1ar[2][8];
    #pragma unroll
    for (int s = 0; s < 2; s++)
        #pragma unroll
        for (int t = 0; t < 8; t++) w1ar[s][t] = w1[2 * (s * 32 + g * 8 + t)];
    // layer-3 weights/bias for this lane's c2 set: c2 = m*16+g*4+r
    float w3r[4][4], b2r[4][4];
    #pragma unroll
    for (int m = 0; m < 4; m++)
        #pragma unroll
        for (int r = 0; r < 4; r++) {
            int c2 = m * 16 + g * 4 + r;
            w3r[m][r] = w3[c2];
            b2r[m][r] = b2[c2];
        }
    __syncthreads();

    for (int ii = 0; ii < 8; ii++) {
        int ix = wid * 8 + ii;
        int iG = iy * 32 + ix;
        float outv = 0.f;
        #pragma unroll
        for (int ntH = 0; ntH < 2; ntH++) {
            // B = h1 fragments: col pair j = nt*16+lr, k = s*32+g*8+t
            short8b bf[2][2];
            #pragma unroll
            for (int ntl = 0; ntl < 2; ntl++) {
                int nt = ntH * 2 + ntl;
                float u0v = u0s[ix * 64 + nt * 16 + lr];
                const float* q1p = &Q1s[(nt * 16 + lr) * 68];
                #pragma unroll
                for (int s = 0; s < 2; s++) {
                    float4 qa = *(const float4*)&q1p[s * 32 + g * 8];
                    float4 qb = *(const float4*)&q1p[s * 32 + g * 8 + 4];
                    short8b f;
                    f[0] = bf16b(fmaxf(fmaf(w1ar[s][0], u0v, qa.x), 0.f));
                    f[1] = bf16b(fmaxf(fmaf(w1ar[s][1], u0v, qa.y), 0.f));
                    f[2] = bf16b(fmaxf(fmaf(w1ar[s][2], u0v, qa.z), 0.f));
                    f[3] = bf16b(fmaxf(fmaf(w1ar[s][3], u0v, qa.w), 0.f));
                    f[4] = bf16b(fmaxf(fmaf(w1ar[s][4], u0v, qb.x), 0.f));
                    f[5] = bf16b(fmaxf(fmaf(w1ar[s][5], u0v, qb.y), 0.f));
                    f[6] = bf16b(fmaxf(fmaf(w1ar[s][6], u0v, qb.z), 0.f));
                    f[7] = bf16b(fmaxf(fmaf(w1ar[s][7], u0v, qb.w), 0.f));
                    bf[ntl][s] = f;
                }
            }
            f32x4 acc[4][2];
            #pragma unroll
            for (int m = 0; m < 4; m++)
                #pragma unroll
                for (int l = 0; l < 2; l++) acc[m][l] = (f32x4){0.f, 0.f, 0.f, 0.f};
            #pragma unroll
            for (int s = 0; s < 2; s++)
                #pragma unroll
                for (int m = 0; m < 4; m++)
                    #pragma unroll
                    for (int l = 0; l < 2; l++)
                        acc[m][l] = __builtin_amdgcn_mfma_f32_16x16x32_bf16(
                            w2f[m][s], bf[l][s], acc[m][l], 0, 0, 0);
            // layer3: lane holds D rows c2=m*16+g*4+r for pairs p=(ntH*2+l)*16+lr
            float t0 = 0.f, t1 = 0.f;
            #pragma unroll
            for (int m = 0; m < 4; m++)
                #pragma unroll
                for (int r = 0; r < 4; r++) {
                    t0 += w3r[m][r] * fmaxf(acc[m][0][r] + b2r[m][r], 0.f);
                    t1 += w3r[m][r] * fmaxf(acc[m][1][r] + b2r[m][r], 0.f);
                }
            t0 += __shfl_xor(t0, 16); t0 += __shfl_xor(t0, 32);
            t1 += __shfl_xor(t1, 16); t1 += __shfl_xor(t1, 32);
            if ((g >> 1) == ntH) outv = (g & 1) ? t1 : t0;
        }
        bias[((size_t)n * 1024 + iG) * 64 + lane] = outv + b3v;
    }
}

// --------- fused attention via MFMA: per wave 16 i x 64 j, no barriers -----
__global__ __launch_bounds__(256) void k_attn(const short* __restrict__ qbt,
                                              const short* __restrict__ kob,
                                              const short* __restrict__ vob,
                                              const float* __restrict__ bias,
                                              float* __restrict__ att) {
    __shared__ float scr[4][1088];   // per-wave: P [16][68] then outT [64][17]
    int it = blockIdx.x, h = blockIdx.y, b = blockIdx.z;
    int n = b * 4 + h;
    int tid = threadIdx.x, wid = tid >> 6, lane = tid & 63, lr = lane & 15, g = lane >> 4;
    int i0w = it * 64 + wid * 16;
    float* P = scr[wid];

    // K B-frags: col j = nt*16+lr, k = d = s*32+g*8+t
    const short* kb = kob + n * 4096;
    short8b kf[4][2];
    #pragma unroll
    for (int nt = 0; nt < 4; nt++)
        #pragma unroll
        for (int s = 0; s < 2; s++)
            kf[nt][s] = *(const short8b*)&kb[(nt * 16 + lr) * 64 + s * 32 + g * 8];
    // V B-frags: col d = nt*16+lr, k = j = s*32+g*8+t
    const short* vb = vob + n * 4096;
    short8b vf[4][2];
    #pragma unroll
    for (int nt = 0; nt < 4; nt++)
        #pragma unroll
        for (int s = 0; s < 2; s++)
            vf[nt][s] = *(const short8b*)&vb[(nt * 16 + lr) * 64 + s * 32 + g * 8];
    // Q A-frag: row i = lr, k = d
    const short* qb = qbt + ((size_t)n * 1024 + i0w + lr) * 64;
    short8b qf[2];
    qf[0] = *(const short8b*)&qb[g * 8];
    qf[1] = *(const short8b*)&qb[32 + g * 8];
    // bias
    float bv[4][4];
    #pragma unroll
    for (int r = 0; r < 4; r++)
        #pragma unroll
        for (int nt = 0; nt < 4; nt++)
            bv[r][nt] = bias[((size_t)n * 1024 + i0w + g * 4 + r) * 64 + nt * 16 + lr];

    // sim = Q K^T
    f32x4 acc[4];
    #pragma unroll
    for (int nt = 0; nt < 4; nt++) acc[nt] = (f32x4){0.f, 0.f, 0.f, 0.f};
    #pragma unroll
    for (int s = 0; s < 2; s++)
        #pragma unroll
        for (int nt = 0; nt < 4; nt++)
            acc[nt] = __builtin_amdgcn_mfma_f32_16x16x32_bf16(qf[s], kf[nt][s], acc[nt], 0, 0, 0);

    // softmax per row (i = g*4+r), cols split over lr(16) x nt(4)
    #pragma unroll
    for (int r = 0; r < 4; r++) {
        float s0 = acc[0][r] + bv[r][0], s1 = acc[1][r] + bv[r][1];
        float s2 = acc[2][r] + bv[r][2], s3 = acc[3][r] + bv[r][3];
        float m = fmaxf(fmaxf(s0, s1), fmaxf(s2, s3));
        m = fmaxf(m, __shfl_xor(m, 1));
        m = fmaxf(m, __shfl_xor(m, 2));
        m = fmaxf(m, __shfl_xor(m, 4));
        m = fmaxf(m, __shfl_xor(m, 8));
        float e0 = __expf(s0 - m), e1 = __expf(s1 - m);
        float e2 = __expf(s2 - m), e3 = __expf(s3 - m);
        float sum = (e0 + e1) + (e2 + e3);
        sum += __shfl_xor(sum, 1);
        sum += __shfl_xor(sum, 2);
        sum += __shfl_xor(sum, 4);
        sum += __shfl_xor(sum, 8);
        float inv = 1.f / sum;
        int row = g * 4 + r;
        P[row * 68 + lr]      = e0 * inv;
        P[row * 68 + 16 + lr] = e1 * inv;
        P[row * 68 + 32 + lr] = e2 * inv;
        P[row * 68 + 48 + lr] = e3 * inv;
    }

    // PV: A = P (row i = lr, k = j), B = V
    const float* pr = &P[lr * 68];
    float4 a0 = *(float4*)&pr[g * 8];
    float4 a1 = *(float4*)&pr[g * 8 + 4];
    float4 a2 = *(float4*)&pr[32 + g * 8];
    float4 a3 = *(float4*)&pr[32 + g * 8 + 4];
    short8b pf0, pf1;
    pf0[0] = bf16b(a0.x); pf0[1] = bf16b(a0.y); pf0[2] = bf16b(a0.z); pf0[3] = bf16b(a0.w);
    pf0[4] = bf16b(a1.x); pf0[5] = bf16b(a1.y); pf0[6] = bf16b(a1.z); pf0[7] = bf16b(a1.w);
    pf1[0] = bf16b(a2.x); pf1[1] = bf16b(a2.y); pf1[2] = bf16b(a2.z); pf1[3] = bf16b(a2.w);
    pf1[4] = bf16b(a3.x); pf1[5] = bf16b(a3.y); pf1[6] = bf16b(a3.z); pf1[7] = bf16b(a3.w);

    f32x4 oacc[4];
    #pragma unroll
    for (int nt = 0; nt < 4; nt++) oacc[nt] = (f32x4){0.f, 0.f, 0.f, 0.f};
    #pragma unroll
    for (int nt = 0; nt < 4; nt++) {
        oacc[nt] = __builtin_amdgcn_mfma_f32_16x16x32_bf16(pf0, vf[nt][0], oacc[nt], 0, 0, 0);
        oacc[nt] = __builtin_amdgcn_mfma_f32_16x16x32_bf16(pf1, vf[nt][1], oacc[nt], 0, 0, 0);
    }

    // transpose out tile via scratch: [d][i16], then coalesced 64B-line stores
    #pragma unroll
    for (int nt = 0; nt < 4; nt++)
        #pragma unroll
        for (int r = 0; r < 4; r++)
            P[(nt * 16 + lr) * 17 + g * 4 + r] = oacc[nt][r];
    float o[16];
    #pragma unroll
    for (int c = 0; c < 16; c++) o[c] = P[lane * 17 + c];
    float* ap = att + ((size_t)(b * 256 + h * 64 + lane)) * 1024 + i0w;
    float4 w0 = {o[0], o[1], o[2], o[3]};
    float4 w1 = {o[4], o[5], o[6], o[7]};
    float4 w2 = {o[8], o[9], o[10], o[11]};
    float4 w3 = {o[12], o[13], o[14], o[15]};
    *(float4*)&ap[0]  = w0;
    *(float4*)&ap[4]  = w1;
    *(float4*)&ap[8]  = w2;
    *(float4*)&ap[12] = w3;
}

// ---------------- output projection: per b 256x256 @ 256x1024 -------------
__global__ __launch_bounds__(256) void k_outproj(const float* __restrict__ att,
                                                 const float* __restrict__ wout,
                                                 const float* __restrict__ bout,
                                                 float* __restrict__ y) {
    __shared__ float Wt[64 * 128];   // [ci][co]
    __shared__ float as[64 * 128];   // [ci][hw]
    int ht = blockIdx.x, ct = blockIdx.y, b = blockIdx.z;
    int tid = threadIdx.x;
    int cg = tid >> 4, hg = tid & 15;
    int co0 = cg * 8, hw0 = hg * 8;
    float acc[8][8] = {};
    for (int kt = 0; kt < 4; kt++) {
        __syncthreads();
        for (int e = tid; e < 8192; e += 256) {
            int co = e >> 6, ci = e & 63;
            Wt[ci * 128 + co] = wout[(ct * 128 + co) * 256 + kt * 64 + ci];
        }
        for (int e = tid; e < 2048; e += 256) {
            int ci = e >> 5, hq = e & 31;
            *(float4*)&as[ci * 128 + hq * 4] =
                *(const float4*)&att[(b * 256 + kt * 64 + ci) * 1024 + ht * 128 + hq * 4];
        }
        __syncthreads();
        for (int ci = 0; ci < 64; ci++) {
            float4 a0 = *(float4*)&Wt[ci * 128 + co0];
            float4 a1 = *(float4*)&Wt[ci * 128 + co0 + 4];
            float4 b0 = *(float4*)&as[ci * 128 + hw0];
            float4 b1 = *(float4*)&as[ci * 128 + hw0 + 4];
            float av[8] = {a0.x, a0.y, a0.z, a0.w, a1.x, a1.y, a1.z, a1.w};
            float bv[8] = {b0.x, b0.y, b0.z, b0.w, b1.x, b1.y, b1.z, b1.w};
            #pragma unroll
            for (int a = 0; a < 8; a++)
                #pragma unroll
                for (int c = 0; c < 8; c++) acc[a][c] += av[a] * bv[c];
        }
    }
    for (int a = 0; a < 8; a++) {
        int co = ct * 128 + co0 + a;
        float bo = bout[co];
        float4 o0 = {acc[a][0] + bo, acc[a][1] + bo, acc[a][2] + bo, acc[a][3] + bo};
        float4 o1 = {acc[a][4] + bo, acc[a][5] + bo, acc[a][6] + bo, acc[a][7] + bo};
        *(float4*)&y[(b * 256 + co) * 1024 + ht * 128 + hw0] = o0;
        *(float4*)&y[(b * 256 + co) * 1024 + ht * 128 + hw0 + 4] = o1;
    }
}

extern "C" void kernel_launch(void* const* d_in, const int* in_sizes, int n_in,
                              void* d_out, int out_size, void* d_ws, size_t ws_size,
                              hipStream_t stream) {
    const float* x    = (const float*)d_in[0];
    const float* wq   = (const float*)d_in[1];
    const float* wk   = (const float*)d_in[2];
    const float* wv   = (const float*)d_in[3];
    const float* wdw  = (const float*)d_in[4];
    const float* bdw  = (const float*)d_in[5];
    const float* wpw  = (const float*)d_in[6];
    const float* cw1  = (const float*)d_in[7];
    const float* cb1  = (const float*)d_in[8];
    const float* cw2  = (const float*)d_in[9];
    const float* cb2  = (const float*)d_in[10];
    const float* cw3  = (const float*)d_in[11];
    const float* cb3  = (const float*)d_in[12];
    const float* wout = (const float*)d_in[13];
    const float* bout = (const float*)d_in[14];
    float* y  = (float*)d_out;
    float* ws = (float*)d_ws;

    float* q    = ws;                          // 2,097,152 f32 (dead after k_dw)
    float* att  = ws;                          // alias: attn output reuses q region
    float* bias = ws + 2097152;                // 2,097,152 f32
    float* kv   = ws + 4194304;                // 131,072 f32
    float* vgs  = ws + 4325376;                // 4,096 f32
    short* qbt  = (short*)(ws + 4329472);      // 2,097,152 bf16
    short* kob  = (short*)(ws + 5378048);      // 131,072 bf16
    short* vob  = (short*)(ws + 5443584);      // 131,072 bf16
    float* gdw  = ws + 5509120;                // 131,072 f32 (gelu(dwconv) scratch)

    k_qproj  <<<dim3(8, 4, 8),  256, 0, stream>>>(x, wq, q, qbt);
    k_dw     <<<dim3(8, 32),    256, 0, stream>>>(q, wdw, bdw, gdw);
    k_pw     <<<32,              64, 0, stream>>>(gdw, wpw, vgs);
    k_sample <<<512,            256, 0, stream>>>(x, vgs, kv);
    k_kvproj <<<32,             256, 0, stream>>>(kv, wk, wv, kob, vob);
    k_cpb    <<<dim3(32, 32),   256, 0, stream>>>(vgs, cw1, cb1, cw2, cb2, cw3, cb3, bias);
    k_attn   <<<dim3(16, 4, 8), 256, 0, stream>>>(qbt, kob, vob, bias, att);
    k_outproj<<<dim3(8, 2, 8),  256, 0, stream>>>(att, wout, bout, y);
}

// Round 6
// 109.157 us; speedup vs baseline: 11.0571x; 1.3620x over previous
//
#include <hip/hip_runtime.h>
#include <hip/hip_bf16.h>
#include <math.h>

#define QSCALE 0.125f

typedef __attribute__((ext_vector_type(8))) short short8b;   // 8 bf16 (4 VGPRs)
typedef __attribute__((ext_vector_type(4))) float f32x4;

// HW packed f32->bf16 (RNE): 1 instr per pair. No builtin on gfx950 (T12).
__device__ __forceinline__ uint pack2(float a, float b) {
    uint r;
    asm("v_cvt_pk_bf16_f32 %0, %1, %2" : "=v"(r) : "v"(a), "v"(b));
    return r;
}
__device__ __forceinline__ float slogf_(float p) {
    return copysignf(log1pf(fabsf(p)), p);
}

// ---------------- q projection: per (b,g) 64x64 @ 64x1024 ----------------
__global__ __launch_bounds__(256) void k_qproj(const float* __restrict__ x,
                                               const float* __restrict__ wq,
                                               float* __restrict__ q,
                                               short* __restrict__ qbt) {
    __shared__ float Wst[64 * 64];   // [ci][co]
    __shared__ float xs[64 * 128];   // [ci][hw]
    int ht = blockIdx.x, g = blockIdx.y, b = blockIdx.z;
    int tid = threadIdx.x;
    for (int e = tid; e < 4096; e += 256) {
        int co = e >> 6, ci = e & 63;
        Wst[ci * 64 + co] = wq[(g * 64 + co) * 64 + ci];
    }
    const float* xb = x + (b * 256 + g * 64) * 1024 + ht * 128;
    for (int e = tid; e < 2048; e += 256) {
        int ci = e >> 5, hq = e & 31;
        *(float4*)&xs[ci * 128 + hq * 4] = *(const float4*)&xb[ci * 1024 + hq * 4];
    }
    __syncthreads();
    int cg = tid >> 4, hg = tid & 15;
    int co0 = cg * 4, hw0 = hg * 8;
    float acc[4][8];
    for (int a = 0; a < 4; a++) for (int c = 0; c < 8; c++) acc[a][c] = 0.f;
    for (int ci = 0; ci < 64; ci++) {
        float4 a4 = *(float4*)&Wst[ci * 64 + co0];
        float4 b0 = *(float4*)&xs[ci * 128 + hw0];
        float4 b1 = *(float4*)&xs[ci * 128 + hw0 + 4];
        float av[4] = {a4.x, a4.y, a4.z, a4.w};
        float bv[8] = {b0.x, b0.y, b0.z, b0.w, b1.x, b1.y, b1.z, b1.w};
        #pragma unroll
        for (int a = 0; a < 4; a++)
            #pragma unroll
            for (int c = 0; c < 8; c++) acc[a][c] += av[a] * bv[c];
    }
    float* qb = q + (b * 256 + g * 64) * 1024 + ht * 128;
    for (int a = 0; a < 4; a++) {
        float4 o0 = {acc[a][0], acc[a][1], acc[a][2], acc[a][3]};
        float4 o1 = {acc[a][4], acc[a][5], acc[a][6], acc[a][7]};
        *(float4*)&qb[(co0 + a) * 1024 + hw0] = o0;
        *(float4*)&qb[(co0 + a) * 1024 + hw0 + 4] = o1;
    }
    short* q16 = qbt + ((size_t)((b * 4 + g) * 1024 + ht * 128)) * 64;
    for (int c = 0; c < 8; c++) {
        int i = hw0 + c;
        uint2 uu;
        uu.x = pack2(acc[0][c] * QSCALE, acc[1][c] * QSCALE);
        uu.y = pack2(acc[2][c] * QSCALE, acc[3][c] * QSCALE);
        *(uint2*)&q16[i * 64 + co0] = uu;
    }
}

// --------- offsets stage 1: depthwise conv6x6 s4 p1 + GELU ---------------
__global__ __launch_bounds__(256) void k_dw(const float* __restrict__ q,
                                            const float* __restrict__ wdw,
                                            const float* __restrict__ bdw,
                                            float* __restrict__ gdw) {
    __shared__ float qs[8 * 1024];
    __shared__ float wds[8 * 36];
    int cg = blockIdx.x, n = blockIdx.y;
    int b = n >> 2, gg = n & 3;
    int c0 = cg * 8;
    int tid = threadIdx.x;
    const float* qn = q + (b * 256 + gg * 64 + c0) * 1024;
    for (int e = tid; e < 2048; e += 256)
        ((float4*)qs)[e] = ((const float4*)qn)[e];
    for (int e = tid; e < 288; e += 256)
        wds[e] = wdw[c0 * 36 + e];
    __syncthreads();
    for (int e = tid; e < 512; e += 256) {
        int c = e >> 6, pos = e & 63;
        int oy = pos >> 3, ox = pos & 7;
        float acc = bdw[c0 + c];
        #pragma unroll
        for (int ky = 0; ky < 6; ky++) {
            int iy = oy * 4 - 1 + ky;
            if (iy < 0 || iy > 31) continue;
            #pragma unroll
            for (int kx = 0; kx < 6; kx++) {
                int ix = ox * 4 - 1 + kx;
                if (ix < 0 || ix > 31) continue;
                acc += qs[c * 1024 + iy * 32 + ix] * wds[c * 36 + ky * 6 + kx];
            }
        }
        gdw[(n * 64 + c0 + c) * 64 + pos] = acc * 0.5f * (1.f + erff(acc * 0.70710678118654752f));
    }
}

// --------- offsets stage 2: 1x1 conv + tanh*4 -> normalized grid ----------
__global__ __launch_bounds__(64) void k_pw(const float* __restrict__ gdw,
                                           const float* __restrict__ wpw,
                                           float* __restrict__ vgs) {
    int n = blockIdx.x, pos = threadIdx.x;
    const float* gp = gdw + n * 4096 + pos;
    float a0 = 0.f, a1 = 0.f;
    #pragma unroll 8
    for (int c = 0; c < 64; c++) {
        float v = gp[c * 64];
        a0 += v * wpw[c];
        a1 += v * wpw[64 + c];
    }
    float offx = tanhf(a0) * 4.0f, offy = tanhf(a1) * 4.0f;
    int oy = pos >> 3, ox = pos & 7;
    vgs[(n * 64 + pos) * 2]     = 2.f * ((float)ox + offx) / 7.f - 1.f;
    vgs[(n * 64 + pos) * 2 + 1] = 2.f * ((float)oy + offy) / 7.f - 1.f;
}

// ------------- grid_sample (bilinear, zeros, align_corners=F) -------------
__global__ __launch_bounds__(256) void k_sample(const float* __restrict__ x,
                                                const float* __restrict__ vgs,
                                                float* __restrict__ kv) {
    int idx = blockIdx.x * 256 + threadIdx.x;
    int pos = idx & 63, c = (idx >> 6) & 63, n = idx >> 12;
    int b = n >> 2, g = n & 3;
    float gx = vgs[(n * 64 + pos) * 2];
    float gy = vgs[(n * 64 + pos) * 2 + 1];
    float ix = (gx + 1.f) * 16.f - 0.5f;
    float iy = (gy + 1.f) * 16.f - 0.5f;
    float x0 = floorf(ix), y0 = floorf(iy);
    float wa = (x0 + 1.f - ix) * (y0 + 1.f - iy);
    float wb = (ix - x0) * (y0 + 1.f - iy);
    float wc = (x0 + 1.f - ix) * (iy - y0);
    float wd = (ix - x0) * (iy - y0);
    const float* img = x + (b * 256 + g * 64 + c) * 1024;
    int xi = (int)x0, yi = (int)y0;
    float acc = 0.f;
    if (xi >= 0 && xi <= 31 && yi >= 0 && yi <= 31)         acc += img[yi * 32 + xi] * wa;
    if (xi + 1 >= 0 && xi + 1 <= 31 && yi >= 0 && yi <= 31) acc += img[yi * 32 + xi + 1] * wb;
    if (xi >= 0 && xi <= 31 && yi + 1 >= 0 && yi + 1 <= 31) acc += img[(yi + 1) * 32 + xi] * wc;
    if (xi + 1 >= 0 && xi + 1 <= 31 && yi + 1 >= 0 && yi + 1 <= 31) acc += img[(yi + 1) * 32 + xi + 1] * wd;
    kv[(n * 64 + c) * 64 + pos] = acc;
}

// -------- k,v projection: per (b,g) two 64x64 @ 64x64 -> bf16 out ---------
__global__ __launch_bounds__(256) void k_kvproj(const float* __restrict__ kv,
                                                const float* __restrict__ wk,
                                                const float* __restrict__ wv,
                                                short* __restrict__ kob,
                                                short* __restrict__ vob) {
    __shared__ float kvs[4096];
    __shared__ float wkt[4096];
    __shared__ float wvt[4096];
    int n = blockIdx.x, g = n & 3;
    int tid = threadIdx.x;
    for (int e = tid; e < 4096; e += 256) {
        int co = e >> 6, ci = e & 63;
        wkt[ci * 64 + co] = wk[(g * 64 + co) * 64 + ci];
        wvt[ci * 64 + co] = wv[(g * 64 + co) * 64 + ci];
        kvs[e] = kv[n * 4096 + e];
    }
    __syncthreads();
    int cg = tid >> 4, jg = tid & 15;
    int co0 = cg * 4, j0 = jg * 4;
    float ak[4][4] = {}, av[4][4] = {};
    for (int ci = 0; ci < 64; ci++) {
        float4 a1 = *(float4*)&wkt[ci * 64 + co0];
        float4 a2 = *(float4*)&wvt[ci * 64 + co0];
        float4 b4 = *(float4*)&kvs[ci * 64 + j0];
        float w1v[4] = {a1.x, a1.y, a1.z, a1.w};
        float w2v[4] = {a2.x, a2.y, a2.z, a2.w};
        float bb[4] = {b4.x, b4.y, b4.z, b4.w};
        #pragma unroll
        for (int a = 0; a < 4; a++)
            #pragma unroll
            for (int j = 0; j < 4; j++) { ak[a][j] += w1v[a] * bb[j]; av[a][j] += w2v[a] * bb[j]; }
    }
    for (int jj = 0; jj < 4; jj++) {
        uint2 uu;
        uu.x = pack2(ak[0][jj], ak[1][jj]);
        uu.y = pack2(ak[2][jj], ak[3][jj]);
        *(uint2*)&kob[n * 4096 + (j0 + jj) * 64 + co0] = uu;
    }
    for (int a = 0; a < 4; a++) {
        uint2 uu;
        uu.x = pack2(av[a][0], av[a][1]);
        uu.y = pack2(av[a][2], av[a][3]);
        *(uint2*)&vob[n * 4096 + (co0 + a) * 64 + j0] = uu;
    }
}

// ----------- wout f32 -> bf16 pre-convert (for MFMA outproj) --------------
__global__ __launch_bounds__(256) void k_wcvt(const float* __restrict__ w,
                                              short* __restrict__ wb) {
    int e = (blockIdx.x * 256 + threadIdx.x) * 8;
    float4 f0 = *(const float4*)&w[e];
    float4 f1 = *(const float4*)&w[e + 4];
    uint4 u = {pack2(f0.x, f0.y), pack2(f0.z, f0.w), pack2(f1.x, f1.y), pack2(f1.z, f1.w)};
    *(uint4*)&wb[e] = u;
}

// ------------------- CPB bias MLP (2->64->64->1) via MFMA -----------------
__global__ __launch_bounds__(256) void k_cpb(const float* __restrict__ vgs,
                                             const float* __restrict__ w1,
                                             const float* __restrict__ b1,
                                             const float* __restrict__ w2,
                                             const float* __restrict__ b2,
                                             const float* __restrict__ w3,
                                             const float* __restrict__ b3,
                                             float* __restrict__ bias) {
    __shared__ float Q1s[64 * 68];   // [j][k] = w1b[k]*u1[j] + b1[k]
    __shared__ float u0s[32 * 64];   // [ix][j] = slog(qx(ix) - kx[j])
    __shared__ float u1t[64];
    int iy = blockIdx.x, n = blockIdx.y, tid = threadIdx.x;
    float qy = 2.f * (float)iy / 31.f - 1.f;

    if (tid < 64) u1t[tid] = slogf_(qy - vgs[(n << 7) + tid * 2 + 1]);
    __syncthreads();
    for (int e = tid; e < 4096; e += 256) {
        int j = e >> 6, k = e & 63;
        Q1s[j * 68 + k] = fmaf(w1[2 * k + 1], u1t[j], b1[k]);
    }
    for (int e = tid; e < 2048; e += 256) {
        int ix = e >> 6, j = e & 63;
        float qx = (2.f / 31.f) * (float)ix - 1.f;
        u0s[e] = slogf_(qx - vgs[(n << 7) + j * 2]);
    }

    int wid = tid >> 6, lane = tid & 63, lr = lane & 15, g = lane >> 4;
    float b3v = b3[0];

    // A = W2 fragments (constant): row c2 = m*16+lr, k = s*32+g*8+t
    short8b w2f[4][2];
    #pragma unroll
    for (int m = 0; m < 4; m++)
        #pragma unroll
        for (int s = 0; s < 2; s++) {
            const float* wp = w2 + (m * 16 + lr) * 64 + s * 32 + g * 8;
            float4 c0 = *(const float4*)wp;
            float4 c1 = *(const float4*)(wp + 4);
            uint4 uu = {pack2(c0.x, c0.y), pack2(c0.z, c0.w),
                        pack2(c1.x, c1.y), pack2(c1.z, c1.w)};
            w2f[m][s] = __builtin_bit_cast(short8b, uu);
        }
    float w1ar[2][8];
    #pragma unroll
    for (int s = 0; s < 2; s++)
        #pragma unroll
        for (int t = 0; t < 8; t++) w1ar[s][t] = w1[2 * (s * 32 + g * 8 + t)];
    // layer-3 weights/bias for this lane's c2 set: c2 = m*16+g*4+r
    float w3r[4][4], b2r[4][4];
    #pragma unroll
    for (int m = 0; m < 4; m++)
        #pragma unroll
        for (int r = 0; r < 4; r++) {
            int c2 = m * 16 + g * 4 + r;
            w3r[m][r] = w3[c2];
            b2r[m][r] = b2[c2];
        }
    __syncthreads();

    for (int ii = 0; ii < 8; ii++) {
        int ix = wid * 8 + ii;
        int iG = iy * 32 + ix;
        float outv = 0.f;
        #pragma unroll
        for (int ntH = 0; ntH < 2; ntH++) {
            short8b bf[2][2];
            #pragma unroll
            for (int ntl = 0; ntl < 2; ntl++) {
                int nt = ntH * 2 + ntl;
                float u0v = u0s[ix * 64 + nt * 16 + lr];
                const float* q1p = &Q1s[(nt * 16 + lr) * 68];
                #pragma unroll
                for (int s = 0; s < 2; s++) {
                    float4 qa = *(const float4*)&q1p[s * 32 + g * 8];
                    float4 qb = *(const float4*)&q1p[s * 32 + g * 8 + 4];
                    float f0 = fmaxf(fmaf(w1ar[s][0], u0v, qa.x), 0.f);
                    float f1 = fmaxf(fmaf(w1ar[s][1], u0v, qa.y), 0.f);
                    float f2 = fmaxf(fmaf(w1ar[s][2], u0v, qa.z), 0.f);
                    float f3 = fmaxf(fmaf(w1ar[s][3], u0v, qa.w), 0.f);
                    float f4 = fmaxf(fmaf(w1ar[s][4], u0v, qb.x), 0.f);
                    float f5 = fmaxf(fmaf(w1ar[s][5], u0v, qb.y), 0.f);
                    float f6 = fmaxf(fmaf(w1ar[s][6], u0v, qb.z), 0.f);
                    float f7 = fmaxf(fmaf(w1ar[s][7], u0v, qb.w), 0.f);
                    uint4 uu = {pack2(f0, f1), pack2(f2, f3), pack2(f4, f5), pack2(f6, f7)};
                    bf[ntl][s] = __builtin_bit_cast(short8b, uu);
                }
            }
            f32x4 acc[4][2];
            #pragma unroll
            for (int m = 0; m < 4; m++)
                #pragma unroll
                for (int l = 0; l < 2; l++)
                    acc[m][l] = (f32x4){b2r[m][0], b2r[m][1], b2r[m][2], b2r[m][3]};
            #pragma unroll
            for (int s = 0; s < 2; s++)
                #pragma unroll
                for (int m = 0; m < 4; m++)
                    #pragma unroll
                    for (int l = 0; l < 2; l++)
                        acc[m][l] = __builtin_amdgcn_mfma_f32_16x16x32_bf16(
                            w2f[m][s], bf[l][s], acc[m][l], 0, 0, 0);
            float t0 = 0.f, t1 = 0.f;
            #pragma unroll
            for (int m = 0; m < 4; m++)
                #pragma unroll
                for (int r = 0; r < 4; r++) {
                    t0 += w3r[m][r] * fmaxf(acc[m][0][r], 0.f);
                    t1 += w3r[m][r] * fmaxf(acc[m][1][r], 0.f);
                }
            t0 += __shfl_xor(t0, 16); t0 += __shfl_xor(t0, 32);
            t1 += __shfl_xor(t1, 16); t1 += __shfl_xor(t1, 32);
            if ((g >> 1) == ntH) outv = (g & 1) ? t1 : t0;
        }
        bias[((size_t)n * 1024 + iG) * 64 + lane] = outv + b3v;
    }
}

// --------- fused attention via MFMA; emits bf16 attb[(b,hw)][ci] ----------
__global__ __launch_bounds__(256) void k_attn(const short* __restrict__ qbt,
                                              const short* __restrict__ kob,
                                              const short* __restrict__ vob,
                                              const float* __restrict__ bias,
                                              short* __restrict__ attb) {
    __shared__ float scr[4][1088];   // per-wave: P [16][68] then outT [64][17]
    int it = blockIdx.x, h = blockIdx.y, b = blockIdx.z;
    int n = b * 4 + h;
    int tid = threadIdx.x, wid = tid >> 6, lane = tid & 63, lr = lane & 15, g = lane >> 4;
    int i0w = it * 64 + wid * 16;
    float* P = scr[wid];

    const short* kb = kob + n * 4096;
    short8b kf[4][2];
    #pragma unroll
    for (int nt = 0; nt < 4; nt++)
        #pragma unroll
        for (int s = 0; s < 2; s++)
            kf[nt][s] = *(const short8b*)&kb[(nt * 16 + lr) * 64 + s * 32 + g * 8];
    const short* vb = vob + n * 4096;
    short8b vf[4][2];
    #pragma unroll
    for (int nt = 0; nt < 4; nt++)
        #pragma unroll
        for (int s = 0; s < 2; s++)
            vf[nt][s] = *(const short8b*)&vb[(nt * 16 + lr) * 64 + s * 32 + g * 8];
    const short* qb = qbt + ((size_t)n * 1024 + i0w + lr) * 64;
    short8b qf[2];
    qf[0] = *(const short8b*)&qb[g * 8];
    qf[1] = *(const short8b*)&qb[32 + g * 8];
    float bv[4][4];
    #pragma unroll
    for (int r = 0; r < 4; r++)
        #pragma unroll
        for (int nt = 0; nt < 4; nt++)
            bv[r][nt] = bias[((size_t)n * 1024 + i0w + g * 4 + r) * 64 + nt * 16 + lr];

    f32x4 acc[4];
    #pragma unroll
    for (int nt = 0; nt < 4; nt++) acc[nt] = (f32x4){0.f, 0.f, 0.f, 0.f};
    #pragma unroll
    for (int s = 0; s < 2; s++)
        #pragma unroll
        for (int nt = 0; nt < 4; nt++)
            acc[nt] = __builtin_amdgcn_mfma_f32_16x16x32_bf16(qf[s], kf[nt][s], acc[nt], 0, 0, 0);

    #pragma unroll
    for (int r = 0; r < 4; r++) {
        float s0 = acc[0][r] + bv[r][0], s1 = acc[1][r] + bv[r][1];
        float s2 = acc[2][r] + bv[r][2], s3 = acc[3][r] + bv[r][3];
        float m = fmaxf(fmaxf(s0, s1), fmaxf(s2, s3));
        m = fmaxf(m, __shfl_xor(m, 1));
        m = fmaxf(m, __shfl_xor(m, 2));
        m = fmaxf(m, __shfl_xor(m, 4));
        m = fmaxf(m, __shfl_xor(m, 8));
        float e0 = __expf(s0 - m), e1 = __expf(s1 - m);
        float e2 = __expf(s2 - m), e3 = __expf(s3 - m);
        float sum = (e0 + e1) + (e2 + e3);
        sum += __shfl_xor(sum, 1);
        sum += __shfl_xor(sum, 2);
        sum += __shfl_xor(sum, 4);
        sum += __shfl_xor(sum, 8);
        float inv = 1.f / sum;
        int row = g * 4 + r;
        P[row * 68 + lr]      = e0 * inv;
        P[row * 68 + 16 + lr] = e1 * inv;
        P[row * 68 + 32 + lr] = e2 * inv;
        P[row * 68 + 48 + lr] = e3 * inv;
    }

    const float* pr = &P[lr * 68];
    float4 a0 = *(float4*)&pr[g * 8];
    float4 a1 = *(float4*)&pr[g * 8 + 4];
    float4 a2 = *(float4*)&pr[32 + g * 8];
    float4 a3 = *(float4*)&pr[32 + g * 8 + 4];
    uint4 up0 = {pack2(a0.x, a0.y), pack2(a0.z, a0.w), pack2(a1.x, a1.y), pack2(a1.z, a1.w)};
    uint4 up1 = {pack2(a2.x, a2.y), pack2(a2.z, a2.w), pack2(a3.x, a3.y), pack2(a3.z, a3.w)};
    short8b pf0 = __builtin_bit_cast(short8b, up0);
    short8b pf1 = __builtin_bit_cast(short8b, up1);

    f32x4 oacc[4];
    #pragma unroll
    for (int nt = 0; nt < 4; nt++) oacc[nt] = (f32x4){0.f, 0.f, 0.f, 0.f};
    #pragma unroll
    for (int nt = 0; nt < 4; nt++) {
        oacc[nt] = __builtin_amdgcn_mfma_f32_16x16x32_bf16(pf0, vf[nt][0], oacc[nt], 0, 0, 0);
        oacc[nt] = __builtin_amdgcn_mfma_f32_16x16x32_bf16(pf1, vf[nt][1], oacc[nt], 0, 0, 0);
    }

    // transpose to [i][d] bf16 via per-wave scratch [d][17]
    #pragma unroll
    for (int nt = 0; nt < 4; nt++)
        #pragma unroll
        for (int r = 0; r < 4; r++)
            P[(nt * 16 + lr) * 17 + g * 4 + r] = oacc[nt][r];
    int il = lane >> 2, dq = lane & 3;
    uint ub[8];
    #pragma unroll
    for (int t = 0; t < 8; t++) {
        float lo = P[(dq * 16 + 2 * t) * 17 + il];
        float hi = P[(dq * 16 + 2 * t + 1) * 17 + il];
        ub[t] = pack2(lo, hi);
    }
    short* op = attb + ((size_t)(b * 1024 + i0w + il)) * 256 + h * 64 + dq * 16;
    uint4 s0v = {ub[0], ub[1], ub[2], ub[3]};
    uint4 s1v = {ub[4], ub[5], ub[6], ub[7]};
    ((uint4*)op)[0] = s0v;
    ((uint4*)op)[1] = s1v;
}

// ------------- output projection via MFMA: C[(b,hw)][co], K=256 -----------
// A = attb rows hw (bf16, direct), B = wob cols co (bf16, direct). No LDS.
__global__ __launch_bounds__(256) void k_outproj(const short* __restrict__ attb,
                                                 const short* __restrict__ wob,
                                                 const float* __restrict__ bout,
                                                 float* __restrict__ y) {
    int rt = blockIdx.x;             // 256: b = rt>>5, hw-tile of 32
    int ct = blockIdx.y;             // 2
    int tid = threadIdx.x, wid = tid >> 6, lane = tid & 63, lr = lane & 15, g = lane >> 4;
    int wr = wid >> 1, wc = wid & 1;
    int b = rt >> 5;
    int hw0 = (rt & 31) * 32 + wr * 16;
    int cobase = ct * 128 + wc * 64;
    const short* arow = attb + ((size_t)(b * 1024) + hw0) * 256;
    const short* brow = wob + (size_t)cobase * 256;

    f32x4 acc[4];
    #pragma unroll
    for (int nn = 0; nn < 4; nn++) acc[nn] = (f32x4){0.f, 0.f, 0.f, 0.f};
    #pragma unroll
    for (int s = 0; s < 8; s++) {
        short8b af = *(const short8b*)&arow[lr * 256 + s * 32 + g * 8];
        #pragma unroll
        for (int nn = 0; nn < 4; nn++) {
            short8b bf = *(const short8b*)&brow[(nn * 16 + lr) * 256 + s * 32 + g * 8];
            acc[nn] = __builtin_amdgcn_mfma_f32_16x16x32_bf16(af, bf, acc[nn], 0, 0, 0);
        }
    }
    #pragma unroll
    for (int nn = 0; nn < 4; nn++) {
        int co = cobase + nn * 16 + lr;
        float bo = bout[co];
        float4 o = {acc[nn][0] + bo, acc[nn][1] + bo, acc[nn][2] + bo, acc[nn][3] + bo};
        *(float4*)&y[(size_t)b * 262144 + (size_t)co * 1024 + hw0 + g * 4] = o;
    }
}

extern "C" void kernel_launch(void* const* d_in, const int* in_sizes, int n_in,
                              void* d_out, int out_size, void* d_ws, size_t ws_size,
                              hipStream_t stream) {
    const float* x    = (const float*)d_in[0];
    const float* wq   = (const float*)d_in[1];
    const float* wk   = (const float*)d_in[2];
    const float* wv   = (const float*)d_in[3];
    const float* wdw  = (const float*)d_in[4];
    const float* bdw  = (const float*)d_in[5];
    const float* wpw  = (const float*)d_in[6];
    const float* cw1  = (const float*)d_in[7];
    const float* cb1  = (const float*)d_in[8];
    const float* cw2  = (const float*)d_in[9];
    const float* cb2  = (const float*)d_in[10];
    const float* cw3  = (const float*)d_in[11];
    const float* cb3  = (const float*)d_in[12];
    const float* wout = (const float*)d_in[13];
    const float* bout = (const float*)d_in[14];
    float* y  = (float*)d_out;
    float* ws = (float*)d_ws;

    float* q    = ws;                          // 8MB f32 (dead after k_dw)
    short* attb = (short*)ws;                  // alias: bf16 attn out [b*hw][ci]
    float* bias = ws + 2097152;
    float* kv   = ws + 4194304;
    float* vgs  = ws + 4325376;
    short* qbt  = (short*)(ws + 4329472);
    short* kob  = (short*)(ws + 5378048);
    short* vob  = (short*)(ws + 5443584);
    float* gdw  = ws + 5509120;
    short* wob  = (short*)(ws + 5640192);      // 65536 bf16

    k_qproj  <<<dim3(8, 4, 8),  256, 0, stream>>>(x, wq, q, qbt);
    k_wcvt   <<<32,             256, 0, stream>>>(wout, wob);
    k_dw     <<<dim3(8, 32),    256, 0, stream>>>(q, wdw, bdw, gdw);
    k_pw     <<<32,              64, 0, stream>>>(gdw, wpw, vgs);
    k_sample <<<512,            256, 0, stream>>>(x, vgs, kv);
    k_kvproj <<<32,             256, 0, stream>>>(kv, wk, wv, kob, vob);
    k_cpb    <<<dim3(32, 32),   256, 0, stream>>>(vgs, cw1, cb1, cw2, cb2, cw3, cb3, bias);
    k_attn   <<<dim3(16, 4, 8), 256, 0, stream>>>(qbt, kob, vob, bias, attb);
    k_outproj<<<dim3(256, 2),   256, 0, stream>>>(attb, wob, bout, y);
}

// Round 7
// 103.938 us; speedup vs baseline: 11.6123x; 1.0502x over previous
//
#include <hip/hip_runtime.h>
#include <hip/hip_bf16.h>
#include <math.h>

#define QSCALE 0.125f

typedef __attribute__((ext_vector_type(8))) short short8b;   // 8 bf16 (4 VGPRs)
typedef __attribute__((ext_vector_type(8))) _Float16 half8;  // 8 f16  (4 VGPRs)
typedef __attribute__((ext_vector_type(4))) float f32x4;

// HW packed f32->bf16 (RNE): 1 instr per pair. No builtin on gfx950 (T12).
__device__ __forceinline__ uint pack2(float a, float b) {
    uint r;
    asm("v_cvt_pk_bf16_f32 %0, %1, %2" : "=v"(r) : "v"(a), "v"(b));
    return r;
}
// packed f32->2xf16 (RTZ), single instr
__device__ __forceinline__ uint pkrtz(float a, float b) {
    uint r;
    asm("v_cvt_pkrtz_f16_f32 %0, %1, %2" : "=v"(r) : "v"(a), "v"(b));
    return r;
}
__device__ __forceinline__ uint pk_fma_f16(uint a, uint b, uint c) {
    uint r;
    asm("v_pk_fma_f16 %0, %1, %2, %3" : "=v"(r) : "v"(a), "v"(b), "v"(c));
    return r;
}
__device__ __forceinline__ uint pk_max_f16(uint a, uint b) {
    uint r;
    asm("v_pk_max_f16 %0, %1, %2" : "=v"(r) : "v"(a), "v"(b));
    return r;
}
__device__ __forceinline__ float slogf_(float p) {
    return copysignf(log1pf(fabsf(p)), p);
}

// ---------------- q projection: per (b,g) 64x64 @ 64x1024 ----------------
__global__ __launch_bounds__(256) void k_qproj(const float* __restrict__ x,
                                               const float* __restrict__ wq,
                                               float* __restrict__ q,
                                               short* __restrict__ qbt) {
    __shared__ float Wst[64 * 64];   // [ci][co]
    __shared__ float xs[64 * 128];   // [ci][hw]
    int ht = blockIdx.x, g = blockIdx.y, b = blockIdx.z;
    int tid = threadIdx.x;
    for (int e = tid; e < 4096; e += 256) {
        int co = e >> 6, ci = e & 63;
        Wst[ci * 64 + co] = wq[(g * 64 + co) * 64 + ci];
    }
    const float* xb = x + (b * 256 + g * 64) * 1024 + ht * 128;
    for (int e = tid; e < 2048; e += 256) {
        int ci = e >> 5, hq = e & 31;
        *(float4*)&xs[ci * 128 + hq * 4] = *(const float4*)&xb[ci * 1024 + hq * 4];
    }
    __syncthreads();
    int cg = tid >> 4, hg = tid & 15;
    int co0 = cg * 4, hw0 = hg * 8;
    float acc[4][8];
    for (int a = 0; a < 4; a++) for (int c = 0; c < 8; c++) acc[a][c] = 0.f;
    for (int ci = 0; ci < 64; ci++) {
        float4 a4 = *(float4*)&Wst[ci * 64 + co0];
        float4 b0 = *(float4*)&xs[ci * 128 + hw0];
        float4 b1 = *(float4*)&xs[ci * 128 + hw0 + 4];
        float av[4] = {a4.x, a4.y, a4.z, a4.w};
        float bv[8] = {b0.x, b0.y, b0.z, b0.w, b1.x, b1.y, b1.z, b1.w};
        #pragma unroll
        for (int a = 0; a < 4; a++)
            #pragma unroll
            for (int c = 0; c < 8; c++) acc[a][c] += av[a] * bv[c];
    }
    float* qb = q + (b * 256 + g * 64) * 1024 + ht * 128;
    for (int a = 0; a < 4; a++) {
        float4 o0 = {acc[a][0], acc[a][1], acc[a][2], acc[a][3]};
        float4 o1 = {acc[a][4], acc[a][5], acc[a][6], acc[a][7]};
        *(float4*)&qb[(co0 + a) * 1024 + hw0] = o0;
        *(float4*)&qb[(co0 + a) * 1024 + hw0 + 4] = o1;
    }
    short* q16 = qbt + ((size_t)((b * 4 + g) * 1024 + ht * 128)) * 64;
    for (int c = 0; c < 8; c++) {
        int i = hw0 + c;
        uint2 uu;
        uu.x = pack2(acc[0][c] * QSCALE, acc[1][c] * QSCALE);
        uu.y = pack2(acc[2][c] * QSCALE, acc[3][c] * QSCALE);
        *(uint2*)&q16[i * 64 + co0] = uu;
    }
}

// --------- offsets stage 1: depthwise conv6x6 s4 p1 + GELU ---------------
__global__ __launch_bounds__(256) void k_dw(const float* __restrict__ q,
                                            const float* __restrict__ wdw,
                                            const float* __restrict__ bdw,
                                            float* __restrict__ gdw) {
    __shared__ float qs[8 * 1024];
    __shared__ float wds[8 * 36];
    int cg = blockIdx.x, n = blockIdx.y;
    int b = n >> 2, gg = n & 3;
    int c0 = cg * 8;
    int tid = threadIdx.x;
    const float* qn = q + (b * 256 + gg * 64 + c0) * 1024;
    for (int e = tid; e < 2048; e += 256)
        ((float4*)qs)[e] = ((const float4*)qn)[e];
    for (int e = tid; e < 288; e += 256)
        wds[e] = wdw[c0 * 36 + e];
    __syncthreads();
    for (int e = tid; e < 512; e += 256) {
        int c = e >> 6, pos = e & 63;
        int oy = pos >> 3, ox = pos & 7;
        float acc = bdw[c0 + c];
        #pragma unroll
        for (int ky = 0; ky < 6; ky++) {
            int iy = oy * 4 - 1 + ky;
            if (iy < 0 || iy > 31) continue;
            #pragma unroll
            for (int kx = 0; kx < 6; kx++) {
                int ix = ox * 4 - 1 + kx;
                if (ix < 0 || ix > 31) continue;
                acc += qs[c * 1024 + iy * 32 + ix] * wds[c * 36 + ky * 6 + kx];
            }
        }
        gdw[(n * 64 + c0 + c) * 64 + pos] = acc * 0.5f * (1.f + erff(acc * 0.70710678118654752f));
    }
}

// --------- offsets stage 2: 1x1 conv + tanh*4 -> normalized grid ----------
__global__ __launch_bounds__(64) void k_pw(const float* __restrict__ gdw,
                                           const float* __restrict__ wpw,
                                           float* __restrict__ vgs) {
    int n = blockIdx.x, pos = threadIdx.x;
    const float* gp = gdw + n * 4096 + pos;
    float a0 = 0.f, a1 = 0.f;
    #pragma unroll 8
    for (int c = 0; c < 64; c++) {
        float v = gp[c * 64];
        a0 += v * wpw[c];
        a1 += v * wpw[64 + c];
    }
    float offx = tanhf(a0) * 4.0f, offy = tanhf(a1) * 4.0f;
    int oy = pos >> 3, ox = pos & 7;
    vgs[(n * 64 + pos) * 2]     = 2.f * ((float)ox + offx) / 7.f - 1.f;
    vgs[(n * 64 + pos) * 2 + 1] = 2.f * ((float)oy + offy) / 7.f - 1.f;
}

// ------------- grid_sample (bilinear, zeros, align_corners=F) -------------
__global__ __launch_bounds__(256) void k_sample(const float* __restrict__ x,
                                                const float* __restrict__ vgs,
                                                float* __restrict__ kv) {
    int idx = blockIdx.x * 256 + threadIdx.x;
    int pos = idx & 63, c = (idx >> 6) & 63, n = idx >> 12;
    int b = n >> 2, g = n & 3;
    float gx = vgs[(n * 64 + pos) * 2];
    float gy = vgs[(n * 64 + pos) * 2 + 1];
    float ix = (gx + 1.f) * 16.f - 0.5f;
    float iy = (gy + 1.f) * 16.f - 0.5f;
    float x0 = floorf(ix), y0 = floorf(iy);
    float wa = (x0 + 1.f - ix) * (y0 + 1.f - iy);
    float wb = (ix - x0) * (y0 + 1.f - iy);
    float wc = (x0 + 1.f - ix) * (iy - y0);
    float wd = (ix - x0) * (iy - y0);
    const float* img = x + (b * 256 + g * 64 + c) * 1024;
    int xi = (int)x0, yi = (int)y0;
    float acc = 0.f;
    if (xi >= 0 && xi <= 31 && yi >= 0 && yi <= 31)         acc += img[yi * 32 + xi] * wa;
    if (xi + 1 >= 0 && xi + 1 <= 31 && yi >= 0 && yi <= 31) acc += img[yi * 32 + xi + 1] * wb;
    if (xi >= 0 && xi <= 31 && yi + 1 >= 0 && yi + 1 <= 31) acc += img[(yi + 1) * 32 + xi] * wc;
    if (xi + 1 >= 0 && xi + 1 <= 31 && yi + 1 >= 0 && yi + 1 <= 31) acc += img[(yi + 1) * 32 + xi + 1] * wd;
    kv[(n * 64 + c) * 64 + pos] = acc;
}

// -------- k,v projection: per (b,g) two 64x64 @ 64x64 -> bf16 out ---------
__global__ __launch_bounds__(256) void k_kvproj(const float* __restrict__ kv,
                                                const float* __restrict__ wk,
                                                const float* __restrict__ wv,
                                                short* __restrict__ kob,
                                                short* __restrict__ vob) {
    __shared__ float kvs[4096];
    __shared__ float wkt[4096];
    __shared__ float wvt[4096];
    int n = blockIdx.x, g = n & 3;
    int tid = threadIdx.x;
    for (int e = tid; e < 4096; e += 256) {
        int co = e >> 6, ci = e & 63;
        wkt[ci * 64 + co] = wk[(g * 64 + co) * 64 + ci];
        wvt[ci * 64 + co] = wv[(g * 64 + co) * 64 + ci];
        kvs[e] = kv[n * 4096 + e];
    }
    __syncthreads();
    int cg = tid >> 4, jg = tid & 15;
    int co0 = cg * 4, j0 = jg * 4;
    float ak[4][4] = {}, av[4][4] = {};
    for (int ci = 0; ci < 64; ci++) {
        float4 a1 = *(float4*)&wkt[ci * 64 + co0];
        float4 a2 = *(float4*)&wvt[ci * 64 + co0];
        float4 b4 = *(float4*)&kvs[ci * 64 + j0];
        float w1v[4] = {a1.x, a1.y, a1.z, a1.w};
        float w2v[4] = {a2.x, a2.y, a2.z, a2.w};
        float bb[4] = {b4.x, b4.y, b4.z, b4.w};
        #pragma unroll
        for (int a = 0; a < 4; a++)
            #pragma unroll
            for (int j = 0; j < 4; j++) { ak[a][j] += w1v[a] * bb[j]; av[a][j] += w2v[a] * bb[j]; }
    }
    for (int jj = 0; jj < 4; jj++) {
        uint2 uu;
        uu.x = pack2(ak[0][jj], ak[1][jj]);
        uu.y = pack2(ak[2][jj], ak[3][jj]);
        *(uint2*)&kob[n * 4096 + (j0 + jj) * 64 + co0] = uu;
    }
    for (int a = 0; a < 4; a++) {
        uint2 uu;
        uu.x = pack2(av[a][0], av[a][1]);
        uu.y = pack2(av[a][2], av[a][3]);
        *(uint2*)&vob[n * 4096 + (co0 + a) * 64 + j0] = uu;
    }
}

// ----------- wout f32 -> bf16 pre-convert (for MFMA outproj) --------------
__global__ __launch_bounds__(256) void k_wcvt(const float* __restrict__ w,
                                              short* __restrict__ wb) {
    int e = (blockIdx.x * 256 + threadIdx.x) * 8;
    float4 f0 = *(const float4*)&w[e];
    float4 f1 = *(const float4*)&w[e + 4];
    uint4 u = {pack2(f0.x, f0.y), pack2(f0.z, f0.w), pack2(f1.x, f1.y), pack2(f1.z, f1.w)};
    *(uint4*)&wb[e] = u;
}

// ------------------- CPB bias MLP (2->64->64->1) via f16 MFMA -------------
// Transposed GEMM: A = W2 (f16, const regs), B = h1 built with packed-f16
// math (v_pk_fma/v_pk_max, 1 inst per 2 values). u0/Q1 pre-packed f16 pairs
// in LDS. C-layout gives each lane 16 c2 for ONE pair -> in-reg layer3.
__global__ __launch_bounds__(256) void k_cpb(const float* __restrict__ vgs,
                                             const float* __restrict__ w1,
                                             const float* __restrict__ b1,
                                             const float* __restrict__ w2,
                                             const float* __restrict__ b2,
                                             const float* __restrict__ w3,
                                             const float* __restrict__ b3,
                                             float* __restrict__ bias) {
    __shared__ uint Q1p[64 * 36];    // [j][k-pair] f16x2: w1b*u1[j]+b1, stride 36 (16B-aligned rows)
    __shared__ uint u0p[32 * 64];    // [ix][j] f16x2 duplicated slog(qx-kx)
    __shared__ float u1t[64];
    int iy = blockIdx.x, n = blockIdx.y, tid = threadIdx.x;
    float qy = 2.f * (float)iy / 31.f - 1.f;

    if (tid < 64) u1t[tid] = slogf_(qy - vgs[(n << 7) + tid * 2 + 1]);
    __syncthreads();
    for (int e = tid; e < 2048; e += 256) {
        int j = e >> 5, pp = e & 31;
        int k = pp * 2;
        float lo = fmaf(w1[2 * k + 1], u1t[j], b1[k]);
        float hi = fmaf(w1[2 * k + 3], u1t[j], b1[k + 1]);
        Q1p[j * 36 + pp] = pkrtz(lo, hi);
    }
    for (int e = tid; e < 2048; e += 256) {
        int ix = e >> 6, j = e & 63;
        float qx = (2.f / 31.f) * (float)ix - 1.f;
        float u = slogf_(qx - vgs[(n << 7) + j * 2]);
        u0p[e] = pkrtz(u, u);
    }

    int wid = tid >> 6, lane = tid & 63, lr = lane & 15, g = lane >> 4;
    float b3v = b3[0];

    // A = W2 f16 fragments (constant): row c2 = m*16+lr, k = s*32+g*8+t
    half8 w2f[4][2];
    #pragma unroll
    for (int m = 0; m < 4; m++)
        #pragma unroll
        for (int s = 0; s < 2; s++) {
            const float* wp = w2 + (m * 16 + lr) * 64 + s * 32 + g * 8;
            float4 c0 = *(const float4*)wp;
            float4 c1 = *(const float4*)(wp + 4);
            uint4 uu = {pkrtz(c0.x, c0.y), pkrtz(c0.z, c0.w),
                        pkrtz(c1.x, c1.y), pkrtz(c1.z, c1.w)};
            w2f[m][s] = __builtin_bit_cast(half8, uu);
        }
    // layer-1 'a' weight pairs (f16x2) for this lane's k-slice
    uint w1ap[2][4];
    #pragma unroll
    for (int s = 0; s < 2; s++)
        #pragma unroll
        for (int p = 0; p < 4; p++) {
            int k = s * 32 + g * 8 + 2 * p;
            w1ap[s][p] = pkrtz(w1[2 * k], w1[2 * k + 2]);
        }
    // layer-3 weights/bias for this lane's c2 set: c2 = m*16+g*4+r
    float w3r[4][4], b2r[4][4];
    #pragma unroll
    for (int m = 0; m < 4; m++)
        #pragma unroll
        for (int r = 0; r < 4; r++) {
            int c2 = m * 16 + g * 4 + r;
            w3r[m][r] = w3[c2];
            b2r[m][r] = b2[c2];
        }
    uint zero16 = 0;
    __syncthreads();

    for (int ii = 0; ii < 8; ii++) {
        int ix = wid * 8 + ii;
        int iG = iy * 32 + ix;
        float outv = 0.f;
        #pragma unroll
        for (int ntH = 0; ntH < 2; ntH++) {
            half8 bf[2][2];
            #pragma unroll
            for (int ntl = 0; ntl < 2; ntl++) {
                int nt = ntH * 2 + ntl;
                uint u0v = u0p[ix * 64 + nt * 16 + lr];
                const uint* q1p = &Q1p[(nt * 16 + lr) * 36];
                #pragma unroll
                for (int s = 0; s < 2; s++) {
                    uint4 q4 = *(const uint4*)&q1p[s * 16 + g * 4];
                    uint4 hb;
                    hb.x = pk_max_f16(pk_fma_f16(w1ap[s][0], u0v, q4.x), zero16);
                    hb.y = pk_max_f16(pk_fma_f16(w1ap[s][1], u0v, q4.y), zero16);
                    hb.z = pk_max_f16(pk_fma_f16(w1ap[s][2], u0v, q4.z), zero16);
                    hb.w = pk_max_f16(pk_fma_f16(w1ap[s][3], u0v, q4.w), zero16);
                    bf[ntl][s] = __builtin_bit_cast(half8, hb);
                }
            }
            f32x4 acc[4][2];
            #pragma unroll
            for (int m = 0; m < 4; m++)
                #pragma unroll
                for (int l = 0; l < 2; l++)
                    acc[m][l] = (f32x4){b2r[m][0], b2r[m][1], b2r[m][2], b2r[m][3]};
            #pragma unroll
            for (int s = 0; s < 2; s++)
                #pragma unroll
                for (int m = 0; m < 4; m++)
                    #pragma unroll
                    for (int l = 0; l < 2; l++)
                        acc[m][l] = __builtin_amdgcn_mfma_f32_16x16x32_f16(
                            w2f[m][s], bf[l][s], acc[m][l], 0, 0, 0);
            float t0 = 0.f, t1 = 0.f;
            #pragma unroll
            for (int m = 0; m < 4; m++)
                #pragma unroll
                for (int r = 0; r < 4; r++) {
                    t0 += w3r[m][r] * fmaxf(acc[m][0][r], 0.f);
                    t1 += w3r[m][r] * fmaxf(acc[m][1][r], 0.f);
                }
            t0 += __shfl_xor(t0, 16); t0 += __shfl_xor(t0, 32);
            t1 += __shfl_xor(t1, 16); t1 += __shfl_xor(t1, 32);
            if ((g >> 1) == ntH) outv = (g & 1) ? t1 : t0;
        }
        bias[((size_t)n * 1024 + iG) * 64 + lane] = outv + b3v;
    }
}

// --------- fused attention via MFMA; emits bf16 attb[(b,hw)][ci] ----------
__global__ __launch_bounds__(256) void k_attn(const short* __restrict__ qbt,
                                              const short* __restrict__ kob,
                                              const short* __restrict__ vob,
                                              const float* __restrict__ bias,
                                              short* __restrict__ attb) {
    __shared__ float scr[4][1088];   // per-wave: P [16][68] then outT [64][17]
    int it = blockIdx.x, h = blockIdx.y, b = blockIdx.z;
    int n = b * 4 + h;
    int tid = threadIdx.x, wid = tid >> 6, lane = tid & 63, lr = lane & 15, g = lane >> 4;
    int i0w = it * 64 + wid * 16;
    float* P = scr[wid];

    const short* kb = kob + n * 4096;
    short8b kf[4][2];
    #pragma unroll
    for (int nt = 0; nt < 4; nt++)
        #pragma unroll
        for (int s = 0; s < 2; s++)
            kf[nt][s] = *(const short8b*)&kb[(nt * 16 + lr) * 64 + s * 32 + g * 8];
    const short* vb = vob + n * 4096;
    short8b vf[4][2];
    #pragma unroll
    for (int nt = 0; nt < 4; nt++)
        #pragma unroll
        for (int s = 0; s < 2; s++)
            vf[nt][s] = *(const short8b*)&vb[(nt * 16 + lr) * 64 + s * 32 + g * 8];
    const short* qb = qbt + ((size_t)n * 1024 + i0w + lr) * 64;
    short8b qf[2];
    qf[0] = *(const short8b*)&qb[g * 8];
    qf[1] = *(const short8b*)&qb[32 + g * 8];
    float bv[4][4];
    #pragma unroll
    for (int r = 0; r < 4; r++)
        #pragma unroll
        for (int nt = 0; nt < 4; nt++)
            bv[r][nt] = bias[((size_t)n * 1024 + i0w + g * 4 + r) * 64 + nt * 16 + lr];

    f32x4 acc[4];
    #pragma unroll
    for (int nt = 0; nt < 4; nt++) acc[nt] = (f32x4){0.f, 0.f, 0.f, 0.f};
    #pragma unroll
    for (int s = 0; s < 2; s++)
        #pragma unroll
        for (int nt = 0; nt < 4; nt++)
            acc[nt] = __builtin_amdgcn_mfma_f32_16x16x32_bf16(qf[s], kf[nt][s], acc[nt], 0, 0, 0);

    #pragma unroll
    for (int r = 0; r < 4; r++) {
        float s0 = acc[0][r] + bv[r][0], s1 = acc[1][r] + bv[r][1];
        float s2 = acc[2][r] + bv[r][2], s3 = acc[3][r] + bv[r][3];
        float m = fmaxf(fmaxf(s0, s1), fmaxf(s2, s3));
        m = fmaxf(m, __shfl_xor(m, 1));
        m = fmaxf(m, __shfl_xor(m, 2));
        m = fmaxf(m, __shfl_xor(m, 4));
        m = fmaxf(m, __shfl_xor(m, 8));
        float e0 = __expf(s0 - m), e1 = __expf(s1 - m);
        float e2 = __expf(s2 - m), e3 = __expf(s3 - m);
        float sum = (e0 + e1) + (e2 + e3);
        sum += __shfl_xor(sum, 1);
        sum += __shfl_xor(sum, 2);
        sum += __shfl_xor(sum, 4);
        sum += __shfl_xor(sum, 8);
        float inv = 1.f / sum;
        int row = g * 4 + r;
        P[row * 68 + lr]      = e0 * inv;
        P[row * 68 + 16 + lr] = e1 * inv;
        P[row * 68 + 32 + lr] = e2 * inv;
        P[row * 68 + 48 + lr] = e3 * inv;
    }

    const float* pr = &P[lr * 68];
    float4 a0 = *(float4*)&pr[g * 8];
    float4 a1 = *(float4*)&pr[g * 8 + 4];
    float4 a2 = *(float4*)&pr[32 + g * 8];
    float4 a3 = *(float4*)&pr[32 + g * 8 + 4];
    uint4 up0 = {pack2(a0.x, a0.y), pack2(a0.z, a0.w), pack2(a1.x, a1.y), pack2(a1.z, a1.w)};
    uint4 up1 = {pack2(a2.x, a2.y), pack2(a2.z, a2.w), pack2(a3.x, a3.y), pack2(a3.z, a3.w)};
    short8b pf0 = __builtin_bit_cast(short8b, up0);
    short8b pf1 = __builtin_bit_cast(short8b, up1);

    f32x4 oacc[4];
    #pragma unroll
    for (int nt = 0; nt < 4; nt++) oacc[nt] = (f32x4){0.f, 0.f, 0.f, 0.f};
    #pragma unroll
    for (int nt = 0; nt < 4; nt++) {
        oacc[nt] = __builtin_amdgcn_mfma_f32_16x16x32_bf16(pf0, vf[nt][0], oacc[nt], 0, 0, 0);
        oacc[nt] = __builtin_amdgcn_mfma_f32_16x16x32_bf16(pf1, vf[nt][1], oacc[nt], 0, 0, 0);
    }

    // transpose to [i][d] bf16 via per-wave scratch [d][17]
    #pragma unroll
    for (int nt = 0; nt < 4; nt++)
        #pragma unroll
        for (int r = 0; r < 4; r++)
            P[(nt * 16 + lr) * 17 + g * 4 + r] = oacc[nt][r];
    int il = lane >> 2, dq = lane & 3;
    uint ub[8];
    #pragma unroll
    for (int t = 0; t < 8; t++) {
        float lo = P[(dq * 16 + 2 * t) * 17 + il];
        float hi = P[(dq * 16 + 2 * t + 1) * 17 + il];
        ub[t] = pack2(lo, hi);
    }
    short* op = attb + ((size_t)(b * 1024 + i0w + il)) * 256 + h * 64 + dq * 16;
    uint4 s0v = {ub[0], ub[1], ub[2], ub[3]};
    uint4 s1v = {ub[4], ub[5], ub[6], ub[7]};
    ((uint4*)op)[0] = s0v;
    ((uint4*)op)[1] = s1v;
}

// ------------- output projection via MFMA: C[(b,hw)][co], K=256 -----------
__global__ __launch_bounds__(256) void k_outproj(const short* __restrict__ attb,
                                                 const short* __restrict__ wob,
                                                 const float* __restrict__ bout,
                                                 float* __restrict__ y) {
    int rt = blockIdx.x;             // 256: b = rt>>5, hw-tile of 32
    int ct = blockIdx.y;             // 2
    int tid = threadIdx.x, wid = tid >> 6, lane = tid & 63, lr = lane & 15, g = lane >> 4;
    int wr = wid >> 1, wc = wid & 1;
    int b = rt >> 5;
    int hw0 = (rt & 31) * 32 + wr * 16;
    int cobase = ct * 128 + wc * 64;
    const short* arow = attb + ((size_t)(b * 1024) + hw0) * 256;
    const short* brow = wob + (size_t)cobase * 256;

    f32x4 acc[4];
    #pragma unroll
    for (int nn = 0; nn < 4; nn++) acc[nn] = (f32x4){0.f, 0.f, 0.f, 0.f};
    #pragma unroll
    for (int s = 0; s < 8; s++) {
        short8b af = *(const short8b*)&arow[lr * 256 + s * 32 + g * 8];
        #pragma unroll
        for (int nn = 0; nn < 4; nn++) {
            short8b bf = *(const short8b*)&brow[(nn * 16 + lr) * 256 + s * 32 + g * 8];
            acc[nn] = __builtin_amdgcn_mfma_f32_16x16x32_bf16(af, bf, acc[nn], 0, 0, 0);
        }
    }
    #pragma unroll
    for (int nn = 0; nn < 4; nn++) {
        int co = cobase + nn * 16 + lr;
        float bo = bout[co];
        float4 o = {acc[nn][0] + bo, acc[nn][1] + bo, acc[nn][2] + bo, acc[nn][3] + bo};
        *(float4*)&y[(size_t)b * 262144 + (size_t)co * 1024 + hw0 + g * 4] = o;
    }
}

extern "C" void kernel_launch(void* const* d_in, const int* in_sizes, int n_in,
                              void* d_out, int out_size, void* d_ws, size_t ws_size,
                              hipStream_t stream) {
    const float* x    = (const float*)d_in[0];
    const float* wq   = (const float*)d_in[1];
    const float* wk   = (const float*)d_in[2];
    const float* wv   = (const float*)d_in[3];
    const float* wdw  = (const float*)d_in[4];
    const float* bdw  = (const float*)d_in[5];
    const float* wpw  = (const float*)d_in[6];
    const float* cw1  = (const float*)d_in[7];
    const float* cb1  = (const float*)d_in[8];
    const float* cw2  = (const float*)d_in[9];
    const float* cb2  = (const float*)d_in[10];
    const float* cw3  = (const float*)d_in[11];
    const float* cb3  = (const float*)d_in[12];
    const float* wout = (const float*)d_in[13];
    const float* bout = (const float*)d_in[14];
    float* y  = (float*)d_out;
    float* ws = (float*)d_ws;

    float* q    = ws;                          // 8MB f32 (dead after k_dw)
    short* attb = (short*)ws;                  // alias: bf16 attn out [b*hw][ci]
    float* bias = ws + 2097152;
    float* kv   = ws + 4194304;
    float* vgs  = ws + 4325376;
    short* qbt  = (short*)(ws + 4329472);
    short* kob  = (short*)(ws + 5378048);
    short* vob  = (short*)(ws + 5443584);
    float* gdw  = ws + 5509120;
    short* wob  = (short*)(ws + 5640192);      // 65536 bf16

    k_qproj  <<<dim3(8, 4, 8),  256, 0, stream>>>(x, wq, q, qbt);
    k_wcvt   <<<32,             256, 0, stream>>>(wout, wob);
    k_dw     <<<dim3(8, 32),    256, 0, stream>>>(q, wdw, bdw, gdw);
    k_pw     <<<32,              64, 0, stream>>>(gdw, wpw, vgs);
    k_sample <<<512,            256, 0, stream>>>(x, vgs, kv);
    k_kvproj <<<32,             256, 0, stream>>>(kv, wk, wv, kob, vob);
    k_cpb    <<<dim3(32, 32),   256, 0, stream>>>(vgs, cw1, cb1, cw2, cb2, cw3, cb3, bias);
    k_attn   <<<dim3(16, 4, 8), 256, 0, stream>>>(qbt, kob, vob, bias, attb);
    k_outproj<<<dim3(256, 2),   256, 0, stream>>>(attb, wob, bout, y);
}